// Round 4
// baseline (1072.195 us; speedup 1.0000x reference)
//
#include <hip/hip_runtime.h>
#include <stdint.h>

#define LSEQ 32768
#define NCH 512      // scan chunks
#define TCH 64       // timesteps per chunk  (NCH*TCH == LSEQ)

typedef _Float16 half8 __attribute__((ext_vector_type(8)));
typedef _Float16 half4v __attribute__((ext_vector_type(4)));
typedef _Float16 half2v __attribute__((ext_vector_type(2)));
typedef float f32x4 __attribute__((ext_vector_type(4)));
typedef float f32x2 __attribute__((ext_vector_type(2)));

__device__ __forceinline__ float sigmoidf_(float x) { return 1.f / (1.f + __expf(-x)); }
__device__ __forceinline__ float gelu_(float x) {
    float z = 0.7978845608028654f * (x + 0.044715f * x * x * x);
    float e = __expf(2.f * z);
    float t = 1.f - 2.f / (e + 1.f);   // tanh(z)
    return 0.5f * x * (1.f + t);
}

// async global->LDS, 16B per lane. LDS dest is wave-uniform base; HW writes
// base + lane*16 (matches the fragment-major chunk layout below).
__device__ __forceinline__ void gll16(const _Float16* gp, _Float16* lp) {
    __builtin_amdgcn_global_load_lds((__attribute__((address_space(1))) void*)gp,
                                     (__attribute__((address_space(3))) void*)lp, 16, 0, 0);
}

// ---------------------------------------------------------------------------
// Generic fp16 MFMA GEMM core: C(BMxBN) = A(M x 256) @ Wt(N x 256)^T
// A row-major (K=256 contig), Wt row-major transposed weight (N rows, K contig).
// Block = 256 threads = 4 waves arranged WR x WC.
// LDS staged fragment-major: chunk(ks, r16) of 64 lanes x 16B, conflict-free b128.
// global_load_lds direct staging + double-buffered prefetch, one barrier/K-step.
// MFMA 16x16x32_f16 layout: Aop[m=lane&15][k=quad*8+j], Bop[k=quad*8+j][n=lane&15],
// D[row=quad*4+r][col=lane&15]  (learn_hip m89/m91-verified).
// ---------------------------------------------------------------------------
template <int BM, int BN, int BK, int WR, int WC>
__device__ __forceinline__ void gemm_core(const _Float16* __restrict__ A,
                                          const _Float16* __restrict__ Wt,
                                          _Float16* sA, _Float16* sW,   // 2*CA*512 / 2*CW*512 halves
                                          int m0, int n0,
                                          f32x4 (&acc)[BM / (WR * 16)][BN / (WC * 16)]) {
    constexpr int MT = BM / (WR * 16);
    constexpr int NT = BN / (WC * 16);
    constexpr int KS = BK / 32;               // 16x16x32 MFMAs per K-step per tile-row
    constexpr int CA = KS * (BM / 16);        // 1KB chunks per A K-step
    constexpr int CW = KS * (BN / 16);
    constexpr int NKB = 256 / BK;
    constexpr int NWAVE = WR * WC;
    const int tid = threadIdx.x;
    const int wid = tid >> 6;
    const int lane = tid & 63;
    const int wm = wid / WC;
    const int wn = wid % WC;

    f32x4 zero = {0.f, 0.f, 0.f, 0.f};
#pragma unroll
    for (int i = 0; i < MT; ++i)
#pragma unroll
        for (int j = 0; j < NT; ++j) acc[i][j] = zero;

    auto stage = [&](int kb, int buf) {
#pragma unroll
        for (int i = 0; i < CA / NWAVE; ++i) {
            int c = i * NWAVE + wid;
            int ks = c / (BM / 16), r16 = c % (BM / 16);
            const _Float16* gp = A + (m0 + r16 * 16 + (lane & 15)) * 256 + kb + ks * 32 + (lane >> 4) * 8;
            gll16(gp, sA + buf * (CA * 512) + c * 512);
        }
#pragma unroll
        for (int i = 0; i < CW / NWAVE; ++i) {
            int c = i * NWAVE + wid;
            int ks = c / (BN / 16), n16 = c % (BN / 16);
            const _Float16* gp = Wt + (n0 + n16 * 16 + (lane & 15)) * 256 + kb + ks * 32 + (lane >> 4) * 8;
            gll16(gp, sW + buf * (CW * 512) + c * 512);
        }
    };

    stage(0, 0);
#pragma unroll
    for (int t = 0; t < NKB; ++t) {
        __syncthreads();                       // drains own vmcnt -> buf(t) ready
        if (t + 1 < NKB) stage((t + 1) * BK, (t + 1) & 1);   // prefetch overlaps MFMAs below
        const _Float16* bA = sA + (t & 1) * (CA * 512);
        const _Float16* bW = sW + (t & 1) * (CW * 512);
#pragma unroll
        for (int ks = 0; ks < KS; ++ks) {
            half8 af[MT], bf[NT];
#pragma unroll
            for (int mt = 0; mt < MT; ++mt)
                af[mt] = *(const half8*)(bA + (ks * (BM / 16) + wm * MT + mt) * 512 + lane * 8);
#pragma unroll
            for (int nt = 0; nt < NT; ++nt)
                bf[nt] = *(const half8*)(bW + (ks * (BN / 16) + wn * NT + nt) * 512 + lane * 8);
#pragma unroll
            for (int mt = 0; mt < MT; ++mt)
#pragma unroll
                for (int nt = 0; nt < NT; ++nt)
                    acc[mt][nt] = __builtin_amdgcn_mfma_f32_16x16x32_f16(af[mt], bf[nt], acc[mt][nt], 0, 0, 0);
        }
    }
    __syncthreads();
}

// --------------------------- setup kernels ---------------------------------
__global__ __launch_bounds__(512) void s5_k0a(const float* __restrict__ lre, const float* __restrict__ lim,
                                              const float* __restrict__ lstep,
                                              float* aR, float* aI, float* cbR, float* cbI,
                                              float* aTR, float* aTI, float* alp, float* ralp) {
    int i = threadIdx.x;  // 4 layers * 128 channels
    float st = expf(lstep[i]);
    float lr = lre[i] * st, li = lim[i] * st;
    float ea = expf(lr);
    float ar = ea * cosf(li), ai = ea * sinf(li);
    float den = lre[i] * lre[i] + lim[i] * lim[i];
    float nr = ar - 1.f, ni = ai;
    float cr = (nr * lre[i] + ni * lim[i]) / den;   // (a-1)/Lambda
    float ci = (ni * lre[i] - nr * lim[i]) / den;
    float cm = sqrtf(cr * cr + ci * ci);
    float al = sqrtf(2.83f / fmaxf(cm, 1e-8f));    // fp16 dynamic-range balancing
    float eT = expf(lr * (float)TCH);
    aR[i] = ar; aI[i] = ai;
    cbR[i] = cr; cbI[i] = ci;
    aTR[i] = eT * cosf(li * (float)TCH);
    aTI[i] = eT * sinf(li * (float)TCH);
    alp[i] = al; ralp[i] = 1.f / al;
}

__global__ __launch_bounds__(256) void s5_k0b(const float* __restrict__ Bre, const float* __restrict__ Bim,
                                              const float* __restrict__ Cre, const float* __restrict__ Cim,
                                              const float* __restrict__ W1, const float* __restrict__ W2,
                                              const float* __restrict__ b1, const float* __restrict__ b2,
                                              const float* __restrict__ Wout,
                                              const float* __restrict__ cbR, const float* __restrict__ cbI,
                                              const float* __restrict__ alp, const float* __restrict__ ralp,
                                              _Float16* Wbu, _Float16* Wc, _Float16* Wglu,
                                              _Float16* WoutT, float* bglu) {
    int stride = gridDim.x * blockDim.x;
    int tid0 = blockIdx.x * blockDim.x + threadIdx.x;
    // Wbu_t[l][n][k]: channels INTERLEAVED: n=2p -> re(Bbar_p), n=2p+1 -> im(Bbar_p);
    // scaled by alpha[p]. k3 then writes Bu[t][2p,2p+1] = (re,im) naturally.
    for (int i = tid0; i < 262144; i += stride) {
        int l = i >> 16, n = (i >> 8) & 255, k = i & 255;
        int p = l * 128 + (n >> 1);
        float re = cbR[p] * Bre[p * 256 + k] - cbI[p] * Bim[p * 256 + k];
        float im = cbR[p] * Bim[p * 256 + k] + cbI[p] * Bre[p * 256 + k];
        Wbu[i] = (_Float16)(((n & 1) ? im : re) * alp[p]);
    }
    // Wc_t[l][n][k]: k-axis interleaved to match xs2: k=2p -> 2*Cre[n][p],
    // k=2p+1 -> -2*Cim[n][p]; scaled by 1/alpha[p]
    for (int i = tid0; i < 262144; i += stride) {
        int l = i >> 16, n = (i >> 8) & 255, k = i & 255;
        int p = k >> 1;
        float base = (k & 1) ? -2.f * Cim[(l * 256 + n) * 128 + p]
                             : 2.f * Cre[(l * 256 + n) * 128 + p];
        Wc[i] = (_Float16)(base * ralp[l * 128 + p]);
    }
    // Wglu_t[l][n][k]: columns permuted so GLU pairs land in the SAME thread:
    // n = 128*y + wn*64 + nt*16 + lm; j = y*64 + wn*32 + (nt>>1)*16 + lm;
    // src = (nt&1) ? W2 : W1.
    for (int i = tid0; i < 524288; i += stride) {
        int l = i >> 17, n = (i >> 8) & 511, k = i & 255;
        int j = ((n >> 7) << 6) | (((n >> 6) & 1) << 5) | (((n >> 5) & 1) << 4) | (n & 15);
        const float* src = ((n >> 4) & 1) ? W2 : W1;
        Wglu[i] = (_Float16)src[(l * 256 + k) * 256 + j];
    }
    for (int i = tid0; i < 16384; i += stride) {
        int n = i >> 8, k = i & 255;
        WoutT[i] = (_Float16)Wout[k * 64 + n];
    }
    for (int i = tid0; i < 2048; i += stride) {
        int l = i >> 9, n = i & 511;
        int j = ((n >> 7) << 6) | (((n >> 6) & 1) << 5) | (((n >> 5) & 1) << 4) | (n & 15);
        bglu[i] = (((n >> 4) & 1) ? b2 : b1)[l * 256 + j];
    }
}

__global__ __launch_bounds__(256) void s5_k0c(const float* __restrict__ latent, const float* __restrict__ W,
                                              const float* __restrict__ b, float* __restrict__ x0) {
    __shared__ float lat[256];
    lat[threadIdx.x] = latent[threadIdx.x];
    __syncthreads();
    float s = b[threadIdx.x];
    for (int k = 0; k < 256; ++k) s += lat[k] * W[k * 256 + threadIdx.x];
    x0[threadIdx.x] = (s > 0.f) ? s : 0.01f * s;   // leaky_relu
}

__global__ __launch_bounds__(256) void s5_k1_fill(const float* __restrict__ x0, float* __restrict__ x) {
    int i = blockIdx.x * 256 + threadIdx.x;       // 8192 blocks: L*256/4 float4s
    f32x4 v = *(const f32x4*)(x0 + (i & 63) * 4);
    *(f32x4*)(x + i * 4) = v;
}

// --------------------------- per-layer kernels -----------------------------
__global__ __launch_bounds__(256) void s5_k2_ln(const float* __restrict__ x, const float* __restrict__ gamma,
                                                const float* __restrict__ beta, _Float16* __restrict__ h) {
    int wid = threadIdx.x >> 6, lane = threadIdx.x & 63;
    int row = blockIdx.x * 4 + wid;
    const float* xr = x + row * 256;
    f32x4 v = *(const f32x4*)(xr + lane * 4);
    float s1 = v[0] + v[1] + v[2] + v[3];
    float s2 = v[0] * v[0] + v[1] * v[1] + v[2] * v[2] + v[3] * v[3];
#pragma unroll
    for (int off = 1; off < 64; off <<= 1) {
        s1 += __shfl_xor(s1, off, 64);
        s2 += __shfl_xor(s2, off, 64);
    }
    float mu = s1 * (1.f / 256.f);
    float var = s2 * (1.f / 256.f) - mu * mu;
    float rs = rsqrtf(fmaxf(var, 0.f) + 1e-6f);
    f32x4 g4 = *(const f32x4*)(gamma + lane * 4);
    f32x4 b4 = *(const f32x4*)(beta + lane * 4);
    half4v o;
#pragma unroll
    for (int j = 0; j < 4; ++j) o[j] = (_Float16)((v[j] - mu) * rs * g4[j] + b4[j]);
    *(half4v*)(h + row * 256 + lane * 4) = o;
}

__global__ __launch_bounds__(256) void s5_k3_gemm_bu(const _Float16* __restrict__ A,
                                                     const _Float16* __restrict__ Wt,
                                                     float* __restrict__ Bu) {
    __shared__ _Float16 sA[2 * 16 * 512], sW[2 * 16 * 512];
    f32x4 acc[4][4];
    int m0 = blockIdx.x * 128, n0 = blockIdx.y * 128;
    gemm_core<128, 128, 64, 2, 2>(A, Wt, sA, sW, m0, n0, acc);
    int tid = threadIdx.x, wid = tid >> 6, lane = tid & 63, lm = lane & 15, quad = lane >> 4;
    int wm = wid >> 1, wn = wid & 1;
#pragma unroll
    for (int mt = 0; mt < 4; ++mt)
#pragma unroll
        for (int nt = 0; nt < 4; ++nt) {
            int col = n0 + wn * 64 + nt * 16 + lm;
#pragma unroll
            for (int r = 0; r < 4; ++r) {
                int row = m0 + wm * 64 + mt * 16 + quad * 4 + r;
                Bu[row * 256 + col] = acc[mt][nt][r];
            }
        }
}

// k4: per-chunk local scan. One f32x2 load per step (interleaved Bu), ALL loads
// issued up-front (full unroll, static indices -> registers), then the serial
// FMA chain, then 16B vector stores to chunk-major xsh.
__global__ __launch_bounds__(128) void s5_k4_scan(const float* __restrict__ Bu,
                                                  const float* __restrict__ aR, const float* __restrict__ aI,
                                                  _Float16* __restrict__ xsh,
                                                  float* __restrict__ carRI) {
    int p = threadIdx.x, c = blockIdx.x;
    float ar = aR[p], ai = aI[p];
    int t0 = c * TCH;
    f32x2 bu[TCH];
#pragma unroll
    for (int j = 0; j < TCH; ++j)
        bu[j] = *(const f32x2*)(Bu + (t0 + j) * 256 + 2 * p);
    float sr = 0.f, si = 0.f;
    _Float16* xb = xsh + (c * 128 + p) * (2 * TCH);   // 256B private row
    half8 ob;
#pragma unroll
    for (int j = 0; j < TCH; ++j) {
        float nr = fmaf(ar, sr, fmaf(-ai, si, bu[j][0]));
        float ni = fmaf(ar, si, fmaf(ai, sr, bu[j][1]));
        sr = nr; si = ni;
        ob[(j & 3) * 2] = (_Float16)sr;
        ob[(j & 3) * 2 + 1] = (_Float16)si;
        if ((j & 3) == 3) *(half8*)(xb + (j - 3) * 2) = ob;
    }
    *(f32x2*)(carRI + (c * 128 + p) * 2) = f32x2{sr, si};
}

// k6: applies carry. Preloads its whole xsh row as 16x half8 (16 outstanding
// 16B loads), computes its own exclusive carry-prefix (f32x2 coalesced,
// L2-resident), writes xs2 interleaved half2 for k7's GEMM.
__global__ __launch_bounds__(128) void s5_k6_apply(const _Float16* __restrict__ xsh,
                                                   const float* __restrict__ carRI,
                                                   const float* __restrict__ aR, const float* __restrict__ aI,
                                                   const float* __restrict__ aTR, const float* __restrict__ aTI,
                                                   _Float16* __restrict__ xs2) {
    int p = threadIdx.x, c = blockIdx.x;
    const _Float16* xb = xsh + (c * 128 + p) * (2 * TCH);
    half8 hh[TCH / 4];
#pragma unroll
    for (int i = 0; i < TCH / 4; ++i)
        hh[i] = *(const half8*)(xb + i * 8);
    float tr = aTR[p], ti = aTI[p];
    float cr = 0.f, ci = 0.f;
    for (int i = 0; i < c; ++i) {                 // exclusive prefix over chunks 0..c-1
        f32x2 w = *(const f32x2*)(carRI + (i * 128 + p) * 2);
        float nr = fmaf(tr, cr, fmaf(-ti, ci, w[0]));
        float ni = fmaf(tr, ci, fmaf(ti, cr, w[1]));
        cr = nr; ci = ni;
    }
    float ar = aR[p], ai = aI[p];
    float fr = ar, fi = ai;       // a^(j+1)
    int t0 = c * TCH;
#pragma unroll
    for (int j = 0; j < TCH; ++j) {
        float xr = (float)hh[j >> 2][(j & 3) * 2]     + fr * cr - fi * ci;
        float xi = (float)hh[j >> 2][(j & 3) * 2 + 1] + fr * ci + fi * cr;
        *(half2v*)(xs2 + (t0 + j) * 256 + 2 * p) = half2v{(_Float16)xr, (_Float16)xi};
        float nr = fr * ar - fi * ai, ni = fr * ai + fi * ar;
        fr = nr; fi = ni;
    }
}

__global__ __launch_bounds__(256) void s5_k7_gemm_c(const _Float16* __restrict__ A,
                                                    const _Float16* __restrict__ Wt,
                                                    const _Float16* __restrict__ h,
                                                    const float* __restrict__ Dv,
                                                    const float* __restrict__ gamma,
                                                    const float* __restrict__ beta,
                                                    _Float16* __restrict__ g) {
    __shared__ _Float16 sA[2 * 4 * 512], sW[2 * 16 * 512];
    __shared__ float red1[64][4], red2[64][4], mu_s[64], rs_s[64];
    f32x4 acc[4][4];
    int m0 = blockIdx.x * 64;
    gemm_core<64, 256, 32, 1, 4>(A, Wt, sA, sW, m0, 0, acc);
    int tid = threadIdx.x, wid = tid >> 6, lane = tid & 63, lm = lane & 15, quad = lane >> 4;
    int wn = wid;
    // y = xs@Wc + h*D
#pragma unroll
    for (int nt = 0; nt < 4; ++nt) {
        int col = wn * 64 + nt * 16 + lm;
        float dv = Dv[col];
#pragma unroll
        for (int mt = 0; mt < 4; ++mt)
#pragma unroll
            for (int r = 0; r < 4; ++r) {
                int row = m0 + mt * 16 + quad * 4 + r;
                acc[mt][nt][r] += (float)h[row * 256 + col] * dv;
            }
    }
    // row stats (LN over 256 cols spread over 4 waves x 4 nt x 16 lanes)
    float s1[4][4], s2[4][4];
#pragma unroll
    for (int mt = 0; mt < 4; ++mt)
#pragma unroll
        for (int r = 0; r < 4; ++r) {
            float a = 0.f, b = 0.f;
#pragma unroll
            for (int nt = 0; nt < 4; ++nt) {
                float v = acc[mt][nt][r];
                a += v; b += v * v;
            }
#pragma unroll
            for (int off = 1; off < 16; off <<= 1) {
                a += __shfl_xor(a, off, 64);
                b += __shfl_xor(b, off, 64);
            }
            s1[mt][r] = a; s2[mt][r] = b;
        }
    if (lm == 0) {
#pragma unroll
        for (int mt = 0; mt < 4; ++mt)
#pragma unroll
            for (int r = 0; r < 4; ++r) {
                int row = mt * 16 + quad * 4 + r;
                red1[row][wid] = s1[mt][r];
                red2[row][wid] = s2[mt][r];
            }
    }
    __syncthreads();
    if (tid < 64) {
        float a = red1[tid][0] + red1[tid][1] + red1[tid][2] + red1[tid][3];
        float b = red2[tid][0] + red2[tid][1] + red2[tid][2] + red2[tid][3];
        float mu = a * (1.f / 256.f);
        float var = b * (1.f / 256.f) - mu * mu;
        mu_s[tid] = mu;
        rs_s[tid] = rsqrtf(fmaxf(var, 0.f) + 1e-6f);
    }
    __syncthreads();
#pragma unroll
    for (int nt = 0; nt < 4; ++nt) {
        int col = wn * 64 + nt * 16 + lm;
        float ga = gamma[col], be = beta[col];
#pragma unroll
        for (int mt = 0; mt < 4; ++mt)
#pragma unroll
            for (int r = 0; r < 4; ++r) {
                int rl = mt * 16 + quad * 4 + r;
                float hn = (acc[mt][nt][r] - mu_s[rl]) * rs_s[rl] * ga + be;
                g[(m0 + rl) * 256 + col] = (_Float16)gelu_(hn);
            }
    }
}

// k8: GLU pairs are in-thread (acc[mt][2p] & acc[mt][2p+1]) thanks to the
// Wglu column permutation -- no shfl, no divergence, all-lane coalesced RMW.
__global__ __launch_bounds__(256) void s5_k8_gemm_glu(const _Float16* __restrict__ A,
                                                      const _Float16* __restrict__ Wt,
                                                      const float* __restrict__ bias,
                                                      float* __restrict__ x,
                                                      _Float16* __restrict__ xh) {
    __shared__ _Float16 sA[2 * 8 * 512], sW[2 * 8 * 512];   // BK=32: 32KB total
    f32x4 acc[4][4];
    int m0 = blockIdx.x * 128, n0 = blockIdx.y * 128;
    gemm_core<128, 128, 32, 2, 2>(A, Wt, sA, sW, m0, n0, acc);
    int tid = threadIdx.x, wid = tid >> 6, lane = tid & 63, lm = lane & 15, quad = lane >> 4;
    int wm = wid >> 1, wn = wid & 1;
    int jbase = (n0 >> 1) + wn * 32 + lm;
#pragma unroll
    for (int mt = 0; mt < 4; ++mt)
#pragma unroll
        for (int p = 0; p < 2; ++p) {
            float b1v = bias[n0 + wn * 64 + (2 * p) * 16 + lm];
            float b2v = bias[n0 + wn * 64 + (2 * p + 1) * 16 + lm];
            int jcol = jbase + p * 16;
#pragma unroll
            for (int r = 0; r < 4; ++r) {
                float u1 = acc[mt][2 * p][r] + b1v;
                float u2 = acc[mt][2 * p + 1][r] + b2v;
                float gl = u1 * sigmoidf_(u2);
                int row = m0 + wm * 64 + mt * 16 + quad * 4 + r;
                int idx = row * 256 + jcol;
                float xn = x[idx] + gl;          // residual
                x[idx] = xn;
                xh[idx] = (_Float16)xn;
            }
        }
}

__global__ __launch_bounds__(256) void s5_k9_gemm_out(const _Float16* __restrict__ A,
                                                      const _Float16* __restrict__ Wt,
                                                      const float* __restrict__ bout,
                                                      float* __restrict__ out) {
    __shared__ _Float16 sA[2 * 16 * 512], sW[2 * 8 * 512];
    f32x4 acc[2][4];
    int m0 = blockIdx.x * 128;
    gemm_core<128, 64, 64, 4, 1>(A, Wt, sA, sW, m0, 0, acc);
    int tid = threadIdx.x, wid = tid >> 6, lane = tid & 63, lm = lane & 15, quad = lane >> 4;
#pragma unroll
    for (int mt = 0; mt < 2; ++mt)
#pragma unroll
        for (int nt = 0; nt < 4; ++nt) {
            int col = nt * 16 + lm;
            float bv = bout[col];
#pragma unroll
            for (int r = 0; r < 4; ++r) {
                int row = m0 + wid * 32 + mt * 16 + quad * 4 + r;
                out[row * 64 + col] = acc[mt][nt][r] + bv;
            }
        }
}

// --------------------------- workspace layout ------------------------------
constexpr size_t OFF_X    = 0;                         // fp32 L*256      33.6MB
constexpr size_t OFF_BU   = 33554432;                  // fp32 L*256 (reused: xs2 half + g half)
constexpr size_t OFF_H    = 67108864;                  // half L*256 (h; reused as xh)
constexpr size_t OFF_XSH  = 83886080;                  // half L*256 (local scans, chunk-major)
constexpr size_t OFF_WBU  = 100663296;                 // half 4*256*256
constexpr size_t OFF_WC   = OFF_WBU + 524288;
constexpr size_t OFF_WGLU = OFF_WC + 524288;           // half 4*512*256
constexpr size_t OFF_WOUT = OFF_WGLU + 1048576;        // half 64*256
constexpr size_t OFF_BGLU = OFF_WOUT + 32768;          // f32 4*512
constexpr size_t OFF_AR   = OFF_BGLU + 8192;
constexpr size_t OFF_AI   = OFF_AR + 2048;
constexpr size_t OFF_CBR  = OFF_AI + 2048;
constexpr size_t OFF_CBI  = OFF_CBR + 2048;
constexpr size_t OFF_ATR  = OFF_CBI + 2048;
constexpr size_t OFF_ATI  = OFF_ATR + 2048;
constexpr size_t OFF_ALP  = OFF_ATI + 2048;
constexpr size_t OFF_RALP = OFF_ALP + 2048;
constexpr size_t OFF_X0   = OFF_RALP + 2048;
constexpr size_t OFF_CARRI= OFF_X0 + 1024;             // f32x2 NCH*128 (512KB)

extern "C" void kernel_launch(void* const* d_in, const int* in_sizes, int n_in,
                              void* d_out, int out_size, void* d_ws, size_t ws_size,
                              hipStream_t stream) {
    (void)in_sizes; (void)n_in; (void)out_size; (void)ws_size;
    const float* latent    = (const float*)d_in[0];
    const float* W_expand  = (const float*)d_in[1];
    const float* b_expand  = (const float*)d_in[2];
    const float* norm_s    = (const float*)d_in[3];
    const float* norm_b    = (const float*)d_in[4];
    const float* Lre       = (const float*)d_in[5];
    const float* Lim       = (const float*)d_in[6];
    const float* Bre       = (const float*)d_in[7];
    const float* Bim       = (const float*)d_in[8];
    const float* Cre       = (const float*)d_in[9];
    const float* Cim       = (const float*)d_in[10];
    const float* Dv        = (const float*)d_in[11];
    const float* lstep     = (const float*)d_in[12];
    const float* W1        = (const float*)d_in[13];
    const float* b1        = (const float*)d_in[14];
    const float* W2        = (const float*)d_in[15];
    const float* b2        = (const float*)d_in[16];
    const float* Wout      = (const float*)d_in[17];
    const float* bout      = (const float*)d_in[18];

    char* ws = (char*)d_ws;
    float*    x    = (float*)(ws + OFF_X);
    float*    Bu   = (float*)(ws + OFF_BU);
    _Float16* xs2  = (_Float16*)(ws + OFF_BU);                 // after k4, Bu region is free
    _Float16* gbuf = (_Float16*)(ws + OFF_BU + 16777216);
    _Float16* hbuf = (_Float16*)(ws + OFF_H);
    _Float16* xh   = (_Float16*)(ws + OFF_H);                  // h dead once k8 runs
    _Float16* xsh  = (_Float16*)(ws + OFF_XSH);
    _Float16* Wbu  = (_Float16*)(ws + OFF_WBU);
    _Float16* Wc   = (_Float16*)(ws + OFF_WC);
    _Float16* Wglu = (_Float16*)(ws + OFF_WGLU);
    _Float16* WoutT= (_Float16*)(ws + OFF_WOUT);
    float* bglu = (float*)(ws + OFF_BGLU);
    float* aR  = (float*)(ws + OFF_AR);
    float* aI  = (float*)(ws + OFF_AI);
    float* cbR = (float*)(ws + OFF_CBR);
    float* cbI = (float*)(ws + OFF_CBI);
    float* aTR = (float*)(ws + OFF_ATR);
    float* aTI = (float*)(ws + OFF_ATI);
    float* alp = (float*)(ws + OFF_ALP);
    float* ralp= (float*)(ws + OFF_RALP);
    float* x0  = (float*)(ws + OFF_X0);
    float* carRI=(float*)(ws + OFF_CARRI);

    s5_k0a<<<1, 512, 0, stream>>>(Lre, Lim, lstep, aR, aI, cbR, cbI, aTR, aTI, alp, ralp);
    s5_k0b<<<256, 256, 0, stream>>>(Bre, Bim, Cre, Cim, W1, W2, b1, b2, Wout,
                                    cbR, cbI, alp, ralp, Wbu, Wc, Wglu, WoutT, bglu);
    s5_k0c<<<1, 256, 0, stream>>>(latent, W_expand, b_expand, x0);
    s5_k1_fill<<<8192, 256, 0, stream>>>(x0, x);

    for (int l = 0; l < 4; ++l) {
        s5_k2_ln<<<8192, 256, 0, stream>>>(x, norm_s + l * 256, norm_b + l * 256, hbuf);
        s5_k3_gemm_bu<<<dim3(256, 2), 256, 0, stream>>>(hbuf, Wbu + l * 65536, Bu);
        s5_k4_scan<<<NCH, 128, 0, stream>>>(Bu, aR + l * 128, aI + l * 128, xsh, carRI);
        s5_k6_apply<<<NCH, 128, 0, stream>>>(xsh, carRI, aR + l * 128, aI + l * 128,
                                             aTR + l * 128, aTI + l * 128, xs2);
        s5_k7_gemm_c<<<512, 256, 0, stream>>>(xs2, Wc + l * 65536, hbuf, Dv + l * 256,
                                              norm_s + l * 256, norm_b + l * 256, gbuf);
        s5_k8_gemm_glu<<<dim3(256, 4), 256, 0, stream>>>(gbuf, Wglu + l * 131072,
                                                         bglu + l * 512, x, xh);
    }
    s5_k9_gemm_out<<<256, 256, 0, stream>>>(xh, WoutT, bout, (float*)d_out);
}

// Round 5
// 656.910 us; speedup vs baseline: 1.6322x; 1.6322x over previous
//
#include <hip/hip_runtime.h>
#include <stdint.h>

#define LSEQ 32768
#define NCH 512      // scan chunks
#define TCH 64       // timesteps per chunk  (NCH*TCH == LSEQ)

typedef _Float16 half8 __attribute__((ext_vector_type(8)));
typedef _Float16 half4v __attribute__((ext_vector_type(4)));
typedef _Float16 half2v __attribute__((ext_vector_type(2)));
typedef float f32x4 __attribute__((ext_vector_type(4)));
typedef float f32x2 __attribute__((ext_vector_type(2)));

__device__ __forceinline__ float sigmoidf_(float x) { return 1.f / (1.f + __expf(-x)); }
__device__ __forceinline__ float gelu_(float x) {
    float z = 0.7978845608028654f * (x + 0.044715f * x * x * x);
    float e = __expf(2.f * z);
    float t = 1.f - 2.f / (e + 1.f);   // tanh(z)
    return 0.5f * x * (1.f + t);
}

// async global->LDS, 16B per lane. LDS dest is wave-uniform base; HW writes
// base + lane*16 (matches the fragment-major chunk layout below).
__device__ __forceinline__ void gll16(const _Float16* gp, _Float16* lp) {
    __builtin_amdgcn_global_load_lds((__attribute__((address_space(1))) void*)gp,
                                     (__attribute__((address_space(3))) void*)lp, 16, 0, 0);
}

// ---------------------------------------------------------------------------
// Generic fp16 MFMA GEMM core: C(BMxBN) = A(M x 256) @ Wt(N x 256)^T
// A row-major (K=256 contig), Wt row-major transposed weight (N rows, K contig).
// Block = 256 threads = 4 waves arranged WR x WC.
// LDS staged fragment-major: chunk(ks, r16) of 64 lanes x 16B, conflict-free b128.
// global_load_lds direct staging + double-buffered prefetch, one barrier/K-step.
// MFMA 16x16x32_f16 layout: Aop[m=lane&15][k=quad*8+j], Bop[k=quad*8+j][n=lane&15],
// D[row=quad*4+r][col=lane&15]  (learn_hip m89/m91-verified).
// ---------------------------------------------------------------------------
template <int BM, int BN, int BK, int WR, int WC>
__device__ __forceinline__ void gemm_core(const _Float16* __restrict__ A,
                                          const _Float16* __restrict__ Wt,
                                          _Float16* sA, _Float16* sW,   // 2*CA*512 / 2*CW*512 halves
                                          int m0, int n0,
                                          f32x4 (&acc)[BM / (WR * 16)][BN / (WC * 16)]) {
    constexpr int MT = BM / (WR * 16);
    constexpr int NT = BN / (WC * 16);
    constexpr int KS = BK / 32;               // 16x16x32 MFMAs per K-step per tile-row
    constexpr int CA = KS * (BM / 16);        // 1KB chunks per A K-step
    constexpr int CW = KS * (BN / 16);
    constexpr int NKB = 256 / BK;
    constexpr int NWAVE = WR * WC;
    const int tid = threadIdx.x;
    const int wid = tid >> 6;
    const int lane = tid & 63;
    const int wm = wid / WC;
    const int wn = wid % WC;

    f32x4 zero = {0.f, 0.f, 0.f, 0.f};
#pragma unroll
    for (int i = 0; i < MT; ++i)
#pragma unroll
        for (int j = 0; j < NT; ++j) acc[i][j] = zero;

    auto stage = [&](int kb, int buf) {
#pragma unroll
        for (int i = 0; i < CA / NWAVE; ++i) {
            int c = i * NWAVE + wid;
            int ks = c / (BM / 16), r16 = c % (BM / 16);
            const _Float16* gp = A + (m0 + r16 * 16 + (lane & 15)) * 256 + kb + ks * 32 + (lane >> 4) * 8;
            gll16(gp, sA + buf * (CA * 512) + c * 512);
        }
#pragma unroll
        for (int i = 0; i < CW / NWAVE; ++i) {
            int c = i * NWAVE + wid;
            int ks = c / (BN / 16), n16 = c % (BN / 16);
            const _Float16* gp = Wt + (n0 + n16 * 16 + (lane & 15)) * 256 + kb + ks * 32 + (lane >> 4) * 8;
            gll16(gp, sW + buf * (CW * 512) + c * 512);
        }
    };

    stage(0, 0);
#pragma unroll
    for (int t = 0; t < NKB; ++t) {
        __syncthreads();                       // drains own vmcnt -> buf(t) ready
        if (t + 1 < NKB) stage((t + 1) * BK, (t + 1) & 1);   // prefetch overlaps MFMAs below
        const _Float16* bA = sA + (t & 1) * (CA * 512);
        const _Float16* bW = sW + (t & 1) * (CW * 512);
#pragma unroll
        for (int ks = 0; ks < KS; ++ks) {
            half8 af[MT], bf[NT];
#pragma unroll
            for (int mt = 0; mt < MT; ++mt)
                af[mt] = *(const half8*)(bA + (ks * (BM / 16) + wm * MT + mt) * 512 + lane * 8);
#pragma unroll
            for (int nt = 0; nt < NT; ++nt)
                bf[nt] = *(const half8*)(bW + (ks * (BN / 16) + wn * NT + nt) * 512 + lane * 8);
#pragma unroll
            for (int mt = 0; mt < MT; ++mt)
#pragma unroll
                for (int nt = 0; nt < NT; ++nt)
                    acc[mt][nt] = __builtin_amdgcn_mfma_f32_16x16x32_f16(af[mt], bf[nt], acc[mt][nt], 0, 0, 0);
        }
    }
    __syncthreads();
}

// --------------------------- setup kernels ---------------------------------
__global__ __launch_bounds__(512) void s5_k0a(const float* __restrict__ lre, const float* __restrict__ lim,
                                              const float* __restrict__ lstep,
                                              float* aR, float* aI, float* cbR, float* cbI,
                                              float* aTR, float* aTI, float* alp, float* ralp) {
    int i = threadIdx.x;  // 4 layers * 128 channels
    float st = expf(lstep[i]);
    float lr = lre[i] * st, li = lim[i] * st;
    float ea = expf(lr);
    float ar = ea * cosf(li), ai = ea * sinf(li);
    float den = lre[i] * lre[i] + lim[i] * lim[i];
    float nr = ar - 1.f, ni = ai;
    float cr = (nr * lre[i] + ni * lim[i]) / den;   // (a-1)/Lambda
    float ci = (ni * lre[i] - nr * lim[i]) / den;
    float cm = sqrtf(cr * cr + ci * ci);
    float al = sqrtf(2.83f / fmaxf(cm, 1e-8f));    // fp16 dynamic-range balancing
    float eT = expf(lr * (float)TCH);
    aR[i] = ar; aI[i] = ai;
    cbR[i] = cr; cbI[i] = ci;
    aTR[i] = eT * cosf(li * (float)TCH);
    aTI[i] = eT * sinf(li * (float)TCH);
    alp[i] = al; ralp[i] = 1.f / al;
}

__global__ __launch_bounds__(256) void s5_k0b(const float* __restrict__ Bre, const float* __restrict__ Bim,
                                              const float* __restrict__ Cre, const float* __restrict__ Cim,
                                              const float* __restrict__ W1, const float* __restrict__ W2,
                                              const float* __restrict__ b1, const float* __restrict__ b2,
                                              const float* __restrict__ Wout,
                                              const float* __restrict__ cbR, const float* __restrict__ cbI,
                                              const float* __restrict__ alp, const float* __restrict__ ralp,
                                              _Float16* Wbu, _Float16* Wc, _Float16* Wglu,
                                              _Float16* WoutT, float* bglu) {
    int stride = gridDim.x * blockDim.x;
    int tid0 = blockIdx.x * blockDim.x + threadIdx.x;
    // Wbu_t[l][n][k]: channels INTERLEAVED: n=2p -> re(Bbar_p), n=2p+1 -> im(Bbar_p);
    // scaled by alpha[p]. k3 then writes Bu[t][2p,2p+1] = (re,im) naturally.
    for (int i = tid0; i < 262144; i += stride) {
        int l = i >> 16, n = (i >> 8) & 255, k = i & 255;
        int p = l * 128 + (n >> 1);
        float re = cbR[p] * Bre[p * 256 + k] - cbI[p] * Bim[p * 256 + k];
        float im = cbR[p] * Bim[p * 256 + k] + cbI[p] * Bre[p * 256 + k];
        Wbu[i] = (_Float16)(((n & 1) ? im : re) * alp[p]);
    }
    // Wc_t[l][n][k]: k-axis interleaved to match xs2: k=2p -> 2*Cre[n][p],
    // k=2p+1 -> -2*Cim[n][p]; scaled by 1/alpha[p]
    for (int i = tid0; i < 262144; i += stride) {
        int l = i >> 16, n = (i >> 8) & 255, k = i & 255;
        int p = k >> 1;
        float base = (k & 1) ? -2.f * Cim[(l * 256 + n) * 128 + p]
                             : 2.f * Cre[(l * 256 + n) * 128 + p];
        Wc[i] = (_Float16)(base * ralp[l * 128 + p]);
    }
    // Wglu_t[l][n][k]: columns permuted so GLU pairs land in the SAME thread:
    // n = 128*y + wn*64 + nt*16 + lm; j = y*64 + wn*32 + (nt>>1)*16 + lm;
    // src = (nt&1) ? W2 : W1.
    for (int i = tid0; i < 524288; i += stride) {
        int l = i >> 17, n = (i >> 8) & 511, k = i & 255;
        int j = ((n >> 7) << 6) | (((n >> 6) & 1) << 5) | (((n >> 5) & 1) << 4) | (n & 15);
        const float* src = ((n >> 4) & 1) ? W2 : W1;
        Wglu[i] = (_Float16)src[(l * 256 + k) * 256 + j];
    }
    for (int i = tid0; i < 16384; i += stride) {
        int n = i >> 8, k = i & 255;
        WoutT[i] = (_Float16)Wout[k * 64 + n];
    }
    for (int i = tid0; i < 2048; i += stride) {
        int l = i >> 9, n = i & 511;
        int j = ((n >> 7) << 6) | (((n >> 6) & 1) << 5) | (((n >> 5) & 1) << 4) | (n & 15);
        bglu[i] = (((n >> 4) & 1) ? b2 : b1)[l * 256 + j];
    }
}

__global__ __launch_bounds__(256) void s5_k0c(const float* __restrict__ latent, const float* __restrict__ W,
                                              const float* __restrict__ b, float* __restrict__ x0) {
    __shared__ float lat[256];
    lat[threadIdx.x] = latent[threadIdx.x];
    __syncthreads();
    float s = b[threadIdx.x];
    for (int k = 0; k < 256; ++k) s += lat[k] * W[k * 256 + threadIdx.x];
    x0[threadIdx.x] = (s > 0.f) ? s : 0.01f * s;   // leaky_relu
}

__global__ __launch_bounds__(256) void s5_k1_fill(const float* __restrict__ x0, float* __restrict__ x) {
    int i = blockIdx.x * 256 + threadIdx.x;       // 8192 blocks: L*256/4 float4s
    f32x4 v = *(const f32x4*)(x0 + (i & 63) * 4);
    *(f32x4*)(x + i * 4) = v;
}

// --------------------------- per-layer kernels -----------------------------
__global__ __launch_bounds__(256) void s5_k2_ln(const float* __restrict__ x, const float* __restrict__ gamma,
                                                const float* __restrict__ beta, _Float16* __restrict__ h) {
    int wid = threadIdx.x >> 6, lane = threadIdx.x & 63;
    int row = blockIdx.x * 4 + wid;
    const float* xr = x + row * 256;
    f32x4 v = *(const f32x4*)(xr + lane * 4);
    float s1 = v[0] + v[1] + v[2] + v[3];
    float s2 = v[0] * v[0] + v[1] * v[1] + v[2] * v[2] + v[3] * v[3];
#pragma unroll
    for (int off = 1; off < 64; off <<= 1) {
        s1 += __shfl_xor(s1, off, 64);
        s2 += __shfl_xor(s2, off, 64);
    }
    float mu = s1 * (1.f / 256.f);
    float var = s2 * (1.f / 256.f) - mu * mu;
    float rs = rsqrtf(fmaxf(var, 0.f) + 1e-6f);
    f32x4 g4 = *(const f32x4*)(gamma + lane * 4);
    f32x4 b4 = *(const f32x4*)(beta + lane * 4);
    half4v o;
#pragma unroll
    for (int j = 0; j < 4; ++j) o[j] = (_Float16)((v[j] - mu) * rs * g4[j] + b4[j]);
    *(half4v*)(h + row * 256 + lane * 4) = o;
}

__global__ __launch_bounds__(256) void s5_k3_gemm_bu(const _Float16* __restrict__ A,
                                                     const _Float16* __restrict__ Wt,
                                                     float* __restrict__ Bu) {
    __shared__ _Float16 sA[2 * 16 * 512], sW[2 * 16 * 512];
    f32x4 acc[4][4];
    int m0 = blockIdx.x * 128, n0 = blockIdx.y * 128;
    gemm_core<128, 128, 64, 2, 2>(A, Wt, sA, sW, m0, n0, acc);
    int tid = threadIdx.x, wid = tid >> 6, lane = tid & 63, lm = lane & 15, quad = lane >> 4;
    int wm = wid >> 1, wn = wid & 1;
#pragma unroll
    for (int mt = 0; mt < 4; ++mt)
#pragma unroll
        for (int nt = 0; nt < 4; ++nt) {
            int col = n0 + wn * 64 + nt * 16 + lm;
#pragma unroll
            for (int r = 0; r < 4; ++r) {
                int row = m0 + wm * 64 + mt * 16 + quad * 4 + r;
                Bu[row * 256 + col] = acc[mt][nt][r];
            }
        }
}

// k4: per-chunk local scan. Interleaved Bu -> one coalesced f32x2 load/step.
// Two-deep group double-buffer (16 loads in flight while chain runs).
// xsh TIME-MAJOR interleaved: xsh[t*256+2p] half2 -> coalesced 4B/lane stores.
__global__ __launch_bounds__(128, 4) void s5_k4_scan(const float* __restrict__ Bu,
                                                     const float* __restrict__ aR, const float* __restrict__ aI,
                                                     _Float16* __restrict__ xsh,
                                                     float* __restrict__ carRI) {
    int p = threadIdx.x, c = blockIdx.x;
    float ar = aR[p], ai = aI[p];
    int t0 = c * TCH;
    const float* bp = Bu + t0 * 256 + 2 * p;
    _Float16* xp = xsh + t0 * 256 + 2 * p;
    f32x2 b0[16], b1[16];
    float sr = 0.f, si = 0.f;

    auto loadg = [&](f32x2 (&buf)[16], int g) {
#pragma unroll
        for (int j = 0; j < 16; ++j) buf[j] = *(const f32x2*)(bp + (g * 16 + j) * 256);
    };
    auto procg = [&](f32x2 (&buf)[16], int g) {
#pragma unroll
        for (int j = 0; j < 16; ++j) {
            float nr = fmaf(ar, sr, fmaf(-ai, si, buf[j][0]));
            float ni = fmaf(ar, si, fmaf(ai, sr, buf[j][1]));
            sr = nr; si = ni;
            *(half2v*)(xp + (g * 16 + j) * 256) = half2v{(_Float16)sr, (_Float16)si};
        }
    };
    loadg(b0, 0);
    loadg(b1, 1);
    procg(b0, 0);
    loadg(b0, 2);
    procg(b1, 1);
    loadg(b1, 3);
    procg(b0, 2);
    procg(b1, 3);
    *(f32x2*)(carRI + (c * 128 + p) * 2) = f32x2{sr, si};
}

// k6: applies carry. Preloads whole chunk as 64 coalesced half2 (static full
// unroll -> registers), own exclusive carry-prefix (unroll 8, L2-resident),
// coalesced half2 stores to xs2.
__global__ __launch_bounds__(128, 4) void s5_k6_apply(const _Float16* __restrict__ xsh,
                                                      const float* __restrict__ carRI,
                                                      const float* __restrict__ aR, const float* __restrict__ aI,
                                                      const float* __restrict__ aTR, const float* __restrict__ aTI,
                                                      _Float16* __restrict__ xs2) {
    int p = threadIdx.x, c = blockIdx.x;
    int t0 = c * TCH;
    const _Float16* xp = xsh + t0 * 256 + 2 * p;
    half2v hv[TCH];
#pragma unroll
    for (int j = 0; j < TCH; ++j) hv[j] = *(const half2v*)(xp + j * 256);
    float tr = aTR[p], ti = aTI[p];
    float cr = 0.f, ci = 0.f;
#pragma unroll 8
    for (int i = 0; i < c; ++i) {                 // exclusive prefix over chunks 0..c-1
        f32x2 w = *(const f32x2*)(carRI + (i * 128 + p) * 2);
        float nr = fmaf(tr, cr, fmaf(-ti, ci, w[0]));
        float ni = fmaf(tr, ci, fmaf(ti, cr, w[1]));
        cr = nr; ci = ni;
    }
    float ar = aR[p], ai = aI[p];
    float fr = ar, fi = ai;       // a^(j+1)
    _Float16* op = xs2 + t0 * 256 + 2 * p;
#pragma unroll
    for (int j = 0; j < TCH; ++j) {
        float xr = (float)hv[j][0] + fr * cr - fi * ci;
        float xi = (float)hv[j][1] + fr * ci + fi * cr;
        *(half2v*)(op + j * 256) = half2v{(_Float16)xr, (_Float16)xi};
        float nr = fr * ar - fi * ai, ni = fr * ai + fi * ar;
        fr = nr; fi = ni;
    }
}

__global__ __launch_bounds__(256) void s5_k7_gemm_c(const _Float16* __restrict__ A,
                                                    const _Float16* __restrict__ Wt,
                                                    const _Float16* __restrict__ h,
                                                    const float* __restrict__ Dv,
                                                    const float* __restrict__ gamma,
                                                    const float* __restrict__ beta,
                                                    _Float16* __restrict__ g) {
    __shared__ _Float16 sA[2 * 4 * 512], sW[2 * 16 * 512];
    __shared__ float red1[64][4], red2[64][4], mu_s[64], rs_s[64];
    f32x4 acc[4][4];
    int m0 = blockIdx.x * 64;
    gemm_core<64, 256, 32, 1, 4>(A, Wt, sA, sW, m0, 0, acc);
    int tid = threadIdx.x, wid = tid >> 6, lane = tid & 63, lm = lane & 15, quad = lane >> 4;
    int wn = wid;
    // y = xs@Wc + h*D
#pragma unroll
    for (int nt = 0; nt < 4; ++nt) {
        int col = wn * 64 + nt * 16 + lm;
        float dv = Dv[col];
#pragma unroll
        for (int mt = 0; mt < 4; ++mt)
#pragma unroll
            for (int r = 0; r < 4; ++r) {
                int row = m0 + mt * 16 + quad * 4 + r;
                acc[mt][nt][r] += (float)h[row * 256 + col] * dv;
            }
    }
    // row stats (LN over 256 cols spread over 4 waves x 4 nt x 16 lanes)
    float s1[4][4], s2[4][4];
#pragma unroll
    for (int mt = 0; mt < 4; ++mt)
#pragma unroll
        for (int r = 0; r < 4; ++r) {
            float a = 0.f, b = 0.f;
#pragma unroll
            for (int nt = 0; nt < 4; ++nt) {
                float v = acc[mt][nt][r];
                a += v; b += v * v;
            }
#pragma unroll
            for (int off = 1; off < 16; off <<= 1) {
                a += __shfl_xor(a, off, 64);
                b += __shfl_xor(b, off, 64);
            }
            s1[mt][r] = a; s2[mt][r] = b;
        }
    if (lm == 0) {
#pragma unroll
        for (int mt = 0; mt < 4; ++mt)
#pragma unroll
            for (int r = 0; r < 4; ++r) {
                int row = mt * 16 + quad * 4 + r;
                red1[row][wid] = s1[mt][r];
                red2[row][wid] = s2[mt][r];
            }
    }
    __syncthreads();
    if (tid < 64) {
        float a = red1[tid][0] + red1[tid][1] + red1[tid][2] + red1[tid][3];
        float b = red2[tid][0] + red2[tid][1] + red2[tid][2] + red2[tid][3];
        float mu = a * (1.f / 256.f);
        float var = b * (1.f / 256.f) - mu * mu;
        mu_s[tid] = mu;
        rs_s[tid] = rsqrtf(fmaxf(var, 0.f) + 1e-6f);
    }
    __syncthreads();
#pragma unroll
    for (int nt = 0; nt < 4; ++nt) {
        int col = wn * 64 + nt * 16 + lm;
        float ga = gamma[col], be = beta[col];
#pragma unroll
        for (int mt = 0; mt < 4; ++mt)
#pragma unroll
            for (int r = 0; r < 4; ++r) {
                int rl = mt * 16 + quad * 4 + r;
                float hn = (acc[mt][nt][r] - mu_s[rl]) * rs_s[rl] * ga + be;
                g[(m0 + rl) * 256 + col] = (_Float16)gelu_(hn);
            }
    }
}

// k8: GLU pairs are in-thread (acc[mt][2p] & acc[mt][2p+1]) thanks to the
// Wglu column permutation -- no shfl, no divergence, all-lane coalesced RMW.
__global__ __launch_bounds__(256) void s5_k8_gemm_glu(const _Float16* __restrict__ A,
                                                      const _Float16* __restrict__ Wt,
                                                      const float* __restrict__ bias,
                                                      float* __restrict__ x,
                                                      _Float16* __restrict__ xh) {
    __shared__ _Float16 sA[2 * 8 * 512], sW[2 * 8 * 512];   // BK=32: 32KB total
    f32x4 acc[4][4];
    int m0 = blockIdx.x * 128, n0 = blockIdx.y * 128;
    gemm_core<128, 128, 32, 2, 2>(A, Wt, sA, sW, m0, n0, acc);
    int tid = threadIdx.x, wid = tid >> 6, lane = tid & 63, lm = lane & 15, quad = lane >> 4;
    int wm = wid >> 1, wn = wid & 1;
    int jbase = (n0 >> 1) + wn * 32 + lm;
#pragma unroll
    for (int mt = 0; mt < 4; ++mt)
#pragma unroll
        for (int p = 0; p < 2; ++p) {
            float b1v = bias[n0 + wn * 64 + (2 * p) * 16 + lm];
            float b2v = bias[n0 + wn * 64 + (2 * p + 1) * 16 + lm];
            int jcol = jbase + p * 16;
#pragma unroll
            for (int r = 0; r < 4; ++r) {
                float u1 = acc[mt][2 * p][r] + b1v;
                float u2 = acc[mt][2 * p + 1][r] + b2v;
                float gl = u1 * sigmoidf_(u2);
                int row = m0 + wm * 64 + mt * 16 + quad * 4 + r;
                int idx = row * 256 + jcol;
                float xn = x[idx] + gl;          // residual
                x[idx] = xn;
                xh[idx] = (_Float16)xn;
            }
        }
}

__global__ __launch_bounds__(256) void s5_k9_gemm_out(const _Float16* __restrict__ A,
                                                      const _Float16* __restrict__ Wt,
                                                      const float* __restrict__ bout,
                                                      float* __restrict__ out) {
    __shared__ _Float16 sA[2 * 16 * 512], sW[2 * 8 * 512];
    f32x4 acc[2][4];
    int m0 = blockIdx.x * 128;
    gemm_core<128, 64, 64, 4, 1>(A, Wt, sA, sW, m0, 0, acc);
    int tid = threadIdx.x, wid = tid >> 6, lane = tid & 63, lm = lane & 15, quad = lane >> 4;
#pragma unroll
    for (int mt = 0; mt < 2; ++mt)
#pragma unroll
        for (int nt = 0; nt < 4; ++nt) {
            int col = nt * 16 + lm;
            float bv = bout[col];
#pragma unroll
            for (int r = 0; r < 4; ++r) {
                int row = m0 + wid * 32 + mt * 16 + quad * 4 + r;
                out[row * 64 + col] = acc[mt][nt][r] + bv;
            }
        }
}

// --------------------------- workspace layout ------------------------------
constexpr size_t OFF_X    = 0;                         // fp32 L*256      33.6MB
constexpr size_t OFF_BU   = 33554432;                  // fp32 L*256 (reused: xs2 half + g half)
constexpr size_t OFF_H    = 67108864;                  // half L*256 (h; reused as xh)
constexpr size_t OFF_XSH  = 83886080;                  // half L*256 (local scans, time-major)
constexpr size_t OFF_WBU  = 100663296;                 // half 4*256*256
constexpr size_t OFF_WC   = OFF_WBU + 524288;
constexpr size_t OFF_WGLU = OFF_WC + 524288;           // half 4*512*256
constexpr size_t OFF_WOUT = OFF_WGLU + 1048576;        // half 64*256
constexpr size_t OFF_BGLU = OFF_WOUT + 32768;          // f32 4*512
constexpr size_t OFF_AR   = OFF_BGLU + 8192;
constexpr size_t OFF_AI   = OFF_AR + 2048;
constexpr size_t OFF_CBR  = OFF_AI + 2048;
constexpr size_t OFF_CBI  = OFF_CBR + 2048;
constexpr size_t OFF_ATR  = OFF_CBI + 2048;
constexpr size_t OFF_ATI  = OFF_ATR + 2048;
constexpr size_t OFF_ALP  = OFF_ATI + 2048;
constexpr size_t OFF_RALP = OFF_ALP + 2048;
constexpr size_t OFF_X0   = OFF_RALP + 2048;
constexpr size_t OFF_CARRI= OFF_X0 + 1024;             // f32x2 NCH*128 (512KB)

extern "C" void kernel_launch(void* const* d_in, const int* in_sizes, int n_in,
                              void* d_out, int out_size, void* d_ws, size_t ws_size,
                              hipStream_t stream) {
    (void)in_sizes; (void)n_in; (void)out_size; (void)ws_size;
    const float* latent    = (const float*)d_in[0];
    const float* W_expand  = (const float*)d_in[1];
    const float* b_expand  = (const float*)d_in[2];
    const float* norm_s    = (const float*)d_in[3];
    const float* norm_b    = (const float*)d_in[4];
    const float* Lre       = (const float*)d_in[5];
    const float* Lim       = (const float*)d_in[6];
    const float* Bre       = (const float*)d_in[7];
    const float* Bim       = (const float*)d_in[8];
    const float* Cre       = (const float*)d_in[9];
    const float* Cim       = (const float*)d_in[10];
    const float* Dv        = (const float*)d_in[11];
    const float* lstep     = (const float*)d_in[12];
    const float* W1        = (const float*)d_in[13];
    const float* b1        = (const float*)d_in[14];
    const float* W2        = (const float*)d_in[15];
    const float* b2        = (const float*)d_in[16];
    const float* Wout      = (const float*)d_in[17];
    const float* bout      = (const float*)d_in[18];

    char* ws = (char*)d_ws;
    float*    x    = (float*)(ws + OFF_X);
    float*    Bu   = (float*)(ws + OFF_BU);
    _Float16* xs2  = (_Float16*)(ws + OFF_BU);                 // after k4, Bu region is free
    _Float16* gbuf = (_Float16*)(ws + OFF_BU + 16777216);
    _Float16* hbuf = (_Float16*)(ws + OFF_H);
    _Float16* xh   = (_Float16*)(ws + OFF_H);                  // h dead once k8 runs
    _Float16* xsh  = (_Float16*)(ws + OFF_XSH);
    _Float16* Wbu  = (_Float16*)(ws + OFF_WBU);
    _Float16* Wc   = (_Float16*)(ws + OFF_WC);
    _Float16* Wglu = (_Float16*)(ws + OFF_WGLU);
    _Float16* WoutT= (_Float16*)(ws + OFF_WOUT);
    float* bglu = (float*)(ws + OFF_BGLU);
    float* aR  = (float*)(ws + OFF_AR);
    float* aI  = (float*)(ws + OFF_AI);
    float* cbR = (float*)(ws + OFF_CBR);
    float* cbI = (float*)(ws + OFF_CBI);
    float* aTR = (float*)(ws + OFF_ATR);
    float* aTI = (float*)(ws + OFF_ATI);
    float* alp = (float*)(ws + OFF_ALP);
    float* ralp= (float*)(ws + OFF_RALP);
    float* x0  = (float*)(ws + OFF_X0);
    float* carRI=(float*)(ws + OFF_CARRI);

    s5_k0a<<<1, 512, 0, stream>>>(Lre, Lim, lstep, aR, aI, cbR, cbI, aTR, aTI, alp, ralp);
    s5_k0b<<<256, 256, 0, stream>>>(Bre, Bim, Cre, Cim, W1, W2, b1, b2, Wout,
                                    cbR, cbI, alp, ralp, Wbu, Wc, Wglu, WoutT, bglu);
    s5_k0c<<<1, 256, 0, stream>>>(latent, W_expand, b_expand, x0);
    s5_k1_fill<<<8192, 256, 0, stream>>>(x0, x);

    for (int l = 0; l < 4; ++l) {
        s5_k2_ln<<<8192, 256, 0, stream>>>(x, norm_s + l * 256, norm_b + l * 256, hbuf);
        s5_k3_gemm_bu<<<dim3(256, 2), 256, 0, stream>>>(hbuf, Wbu + l * 65536, Bu);
        s5_k4_scan<<<NCH, 128, 0, stream>>>(Bu, aR + l * 128, aI + l * 128, xsh, carRI);
        s5_k6_apply<<<NCH, 128, 0, stream>>>(xsh, carRI, aR + l * 128, aI + l * 128,
                                             aTR + l * 128, aTI + l * 128, xs2);
        s5_k7_gemm_c<<<512, 256, 0, stream>>>(xs2, Wc + l * 65536, hbuf, Dv + l * 256,
                                              norm_s + l * 256, norm_b + l * 256, gbuf);
        s5_k8_gemm_glu<<<dim3(256, 4), 256, 0, stream>>>(gbuf, Wglu + l * 131072,
                                                         bglu + l * 512, x, xh);
    }
    s5_k9_gemm_out<<<256, 256, 0, stream>>>(xh, WoutT, bout, (float*)d_out);
}

// Round 6
// 642.598 us; speedup vs baseline: 1.6685x; 1.0223x over previous
//
#include <hip/hip_runtime.h>
#include <stdint.h>

#define LSEQ 32768
#define NCH 512      // scan chunks
#define TCH 64       // timesteps per chunk  (NCH*TCH == LSEQ)

typedef _Float16 half8 __attribute__((ext_vector_type(8)));
typedef _Float16 half4v __attribute__((ext_vector_type(4)));
typedef _Float16 half2v __attribute__((ext_vector_type(2)));
typedef float f32x4 __attribute__((ext_vector_type(4)));
typedef float f32x2 __attribute__((ext_vector_type(2)));

__device__ __forceinline__ float sigmoidf_(float x) { return 1.f / (1.f + __expf(-x)); }
__device__ __forceinline__ float gelu_(float x) {
    float z = 0.7978845608028654f * (x + 0.044715f * x * x * x);
    float e = __expf(2.f * z);
    float t = 1.f - 2.f / (e + 1.f);   // tanh(z)
    return 0.5f * x * (1.f + t);
}

// async global->LDS, 16B per lane. LDS dest is wave-uniform base; HW writes
// base + lane*16 (matches the fragment-major chunk layout below).
__device__ __forceinline__ void gll16(const _Float16* gp, _Float16* lp) {
    __builtin_amdgcn_global_load_lds((__attribute__((address_space(1))) void*)gp,
                                     (__attribute__((address_space(3))) void*)lp, 16, 0, 0);
}

// ---------------------------------------------------------------------------
// Generic fp16 MFMA GEMM core: C(BMxBN) = A(M x 256) @ Wt(N x 256)^T
// (old barrier-per-K-step core; still used by k3/k7/k9 as controls)
// ---------------------------------------------------------------------------
template <int BM, int BN, int BK, int WR, int WC>
__device__ __forceinline__ void gemm_core(const _Float16* __restrict__ A,
                                          const _Float16* __restrict__ Wt,
                                          _Float16* sA, _Float16* sW,   // 2*CA*512 / 2*CW*512 halves
                                          int m0, int n0,
                                          f32x4 (&acc)[BM / (WR * 16)][BN / (WC * 16)]) {
    constexpr int MT = BM / (WR * 16);
    constexpr int NT = BN / (WC * 16);
    constexpr int KS = BK / 32;               // 16x16x32 MFMAs per K-step per tile-row
    constexpr int CA = KS * (BM / 16);        // 1KB chunks per A K-step
    constexpr int CW = KS * (BN / 16);
    constexpr int NKB = 256 / BK;
    constexpr int NWAVE = WR * WC;
    const int tid = threadIdx.x;
    const int wid = tid >> 6;
    const int lane = tid & 63;
    const int wm = wid / WC;
    const int wn = wid % WC;

    f32x4 zero = {0.f, 0.f, 0.f, 0.f};
#pragma unroll
    for (int i = 0; i < MT; ++i)
#pragma unroll
        for (int j = 0; j < NT; ++j) acc[i][j] = zero;

    auto stage = [&](int kb, int buf) {
#pragma unroll
        for (int i = 0; i < CA / NWAVE; ++i) {
            int c = i * NWAVE + wid;
            int ks = c / (BM / 16), r16 = c % (BM / 16);
            const _Float16* gp = A + (m0 + r16 * 16 + (lane & 15)) * 256 + kb + ks * 32 + (lane >> 4) * 8;
            gll16(gp, sA + buf * (CA * 512) + c * 512);
        }
#pragma unroll
        for (int i = 0; i < CW / NWAVE; ++i) {
            int c = i * NWAVE + wid;
            int ks = c / (BN / 16), n16 = c % (BN / 16);
            const _Float16* gp = Wt + (n0 + n16 * 16 + (lane & 15)) * 256 + kb + ks * 32 + (lane >> 4) * 8;
            gll16(gp, sW + buf * (CW * 512) + c * 512);
        }
    };

    stage(0, 0);
#pragma unroll
    for (int t = 0; t < NKB; ++t) {
        __syncthreads();                       // drains own vmcnt -> buf(t) ready
        if (t + 1 < NKB) stage((t + 1) * BK, (t + 1) & 1);   // prefetch overlaps MFMAs below
        const _Float16* bA = sA + (t & 1) * (CA * 512);
        const _Float16* bW = sW + (t & 1) * (CW * 512);
#pragma unroll
        for (int ks = 0; ks < KS; ++ks) {
            half8 af[MT], bf[NT];
#pragma unroll
            for (int mt = 0; mt < MT; ++mt)
                af[mt] = *(const half8*)(bA + (ks * (BM / 16) + wm * MT + mt) * 512 + lane * 8);
#pragma unroll
            for (int nt = 0; nt < NT; ++nt)
                bf[nt] = *(const half8*)(bW + (ks * (BN / 16) + wn * NT + nt) * 512 + lane * 8);
#pragma unroll
            for (int mt = 0; mt < MT; ++mt)
#pragma unroll
                for (int nt = 0; nt < NT; ++nt)
                    acc[mt][nt] = __builtin_amdgcn_mfma_f32_16x16x32_f16(af[mt], bf[nt], acc[mt][nt], 0, 0, 0);
        }
    }
    __syncthreads();
}

// --------------------------- setup kernels ---------------------------------
__global__ __launch_bounds__(512) void s5_k0a(const float* __restrict__ lre, const float* __restrict__ lim,
                                              const float* __restrict__ lstep,
                                              float* aR, float* aI, float* cbR, float* cbI,
                                              float* aTR, float* aTI, float* alp, float* ralp) {
    int i = threadIdx.x;  // 4 layers * 128 channels
    float st = expf(lstep[i]);
    float lr = lre[i] * st, li = lim[i] * st;
    float ea = expf(lr);
    float ar = ea * cosf(li), ai = ea * sinf(li);
    float den = lre[i] * lre[i] + lim[i] * lim[i];
    float nr = ar - 1.f, ni = ai;
    float cr = (nr * lre[i] + ni * lim[i]) / den;   // (a-1)/Lambda
    float ci = (ni * lre[i] - nr * lim[i]) / den;
    float cm = sqrtf(cr * cr + ci * ci);
    float al = sqrtf(2.83f / fmaxf(cm, 1e-8f));    // fp16 dynamic-range balancing
    float eT = expf(lr * (float)TCH);
    aR[i] = ar; aI[i] = ai;
    cbR[i] = cr; cbI[i] = ci;
    aTR[i] = eT * cosf(li * (float)TCH);
    aTI[i] = eT * sinf(li * (float)TCH);
    alp[i] = al; ralp[i] = 1.f / al;
}

__global__ __launch_bounds__(256) void s5_k0b(const float* __restrict__ Bre, const float* __restrict__ Bim,
                                              const float* __restrict__ Cre, const float* __restrict__ Cim,
                                              const float* __restrict__ W1, const float* __restrict__ W2,
                                              const float* __restrict__ b1, const float* __restrict__ b2,
                                              const float* __restrict__ Wout,
                                              const float* __restrict__ cbR, const float* __restrict__ cbI,
                                              const float* __restrict__ alp, const float* __restrict__ ralp,
                                              _Float16* Wbu, _Float16* Wc, _Float16* Wglu,
                                              _Float16* WoutT, float* bglu) {
    int stride = gridDim.x * blockDim.x;
    int tid0 = blockIdx.x * blockDim.x + threadIdx.x;
    // Wbu_t[l][n][k]: channels INTERLEAVED: n=2p -> re(Bbar_p), n=2p+1 -> im(Bbar_p);
    // scaled by alpha[p]. k3 then writes Bu[t][2p,2p+1] = (re,im) naturally.
    for (int i = tid0; i < 262144; i += stride) {
        int l = i >> 16, n = (i >> 8) & 255, k = i & 255;
        int p = l * 128 + (n >> 1);
        float re = cbR[p] * Bre[p * 256 + k] - cbI[p] * Bim[p * 256 + k];
        float im = cbR[p] * Bim[p * 256 + k] + cbI[p] * Bre[p * 256 + k];
        Wbu[i] = (_Float16)(((n & 1) ? im : re) * alp[p]);
    }
    // Wc_t[l][n][k]: k-axis interleaved to match xs2: k=2p -> 2*Cre[n][p],
    // k=2p+1 -> -2*Cim[n][p]; scaled by 1/alpha[p]
    for (int i = tid0; i < 262144; i += stride) {
        int l = i >> 16, n = (i >> 8) & 255, k = i & 255;
        int p = k >> 1;
        float base = (k & 1) ? -2.f * Cim[(l * 256 + n) * 128 + p]
                             : 2.f * Cre[(l * 256 + n) * 128 + p];
        Wc[i] = (_Float16)(base * ralp[l * 128 + p]);
    }
    // Wglu_t[l][n][k]: columns permuted so GLU pairs land in the SAME thread:
    // n = 128*y + t*16 + lm; j = y*64 + (t>>2)*32 + ((t>>1)&1)*16 + lm;
    // src = (t&1) ? W2 : W1.
    for (int i = tid0; i < 524288; i += stride) {
        int l = i >> 17, n = (i >> 8) & 511, k = i & 255;
        int j = ((n >> 7) << 6) | (((n >> 6) & 1) << 5) | (((n >> 5) & 1) << 4) | (n & 15);
        const float* src = ((n >> 4) & 1) ? W2 : W1;
        Wglu[i] = (_Float16)src[(l * 256 + k) * 256 + j];
    }
    for (int i = tid0; i < 16384; i += stride) {
        int n = i >> 8, k = i & 255;
        WoutT[i] = (_Float16)Wout[k * 64 + n];
    }
    for (int i = tid0; i < 2048; i += stride) {
        int l = i >> 9, n = i & 511;
        int j = ((n >> 7) << 6) | (((n >> 6) & 1) << 5) | (((n >> 5) & 1) << 4) | (n & 15);
        bglu[i] = (((n >> 4) & 1) ? b2 : b1)[l * 256 + j];
    }
}

__global__ __launch_bounds__(256) void s5_k0c(const float* __restrict__ latent, const float* __restrict__ W,
                                              const float* __restrict__ b, float* __restrict__ x0) {
    __shared__ float lat[256];
    lat[threadIdx.x] = latent[threadIdx.x];
    __syncthreads();
    float s = b[threadIdx.x];
    for (int k = 0; k < 256; ++k) s += lat[k] * W[k * 256 + threadIdx.x];
    x0[threadIdx.x] = (s > 0.f) ? s : 0.01f * s;   // leaky_relu
}

__global__ __launch_bounds__(256) void s5_k1_fill(const float* __restrict__ x0, float* __restrict__ x) {
    int i = blockIdx.x * 256 + threadIdx.x;       // 8192 blocks: L*256/4 float4s
    f32x4 v = *(const f32x4*)(x0 + (i & 63) * 4);
    *(f32x4*)(x + i * 4) = v;
}

// --------------------------- per-layer kernels -----------------------------
__global__ __launch_bounds__(256) void s5_k2_ln(const float* __restrict__ x, const float* __restrict__ gamma,
                                                const float* __restrict__ beta, _Float16* __restrict__ h) {
    int wid = threadIdx.x >> 6, lane = threadIdx.x & 63;
    int row = blockIdx.x * 4 + wid;
    const float* xr = x + row * 256;
    f32x4 v = *(const f32x4*)(xr + lane * 4);
    float s1 = v[0] + v[1] + v[2] + v[3];
    float s2 = v[0] * v[0] + v[1] * v[1] + v[2] * v[2] + v[3] * v[3];
#pragma unroll
    for (int off = 1; off < 64; off <<= 1) {
        s1 += __shfl_xor(s1, off, 64);
        s2 += __shfl_xor(s2, off, 64);
    }
    float mu = s1 * (1.f / 256.f);
    float var = s2 * (1.f / 256.f) - mu * mu;
    float rs = rsqrtf(fmaxf(var, 0.f) + 1e-6f);
    f32x4 g4 = *(const f32x4*)(gamma + lane * 4);
    f32x4 b4 = *(const f32x4*)(beta + lane * 4);
    half4v o;
#pragma unroll
    for (int j = 0; j < 4; ++j) o[j] = (_Float16)((v[j] - mu) * rs * g4[j] + b4[j]);
    *(half4v*)(h + row * 256 + lane * 4) = o;
}

__global__ __launch_bounds__(256) void s5_k3_gemm_bu(const _Float16* __restrict__ A,
                                                     const _Float16* __restrict__ Wt,
                                                     float* __restrict__ Bu) {
    __shared__ _Float16 sA[2 * 16 * 512], sW[2 * 16 * 512];
    f32x4 acc[4][4];
    int m0 = blockIdx.x * 128, n0 = blockIdx.y * 128;
    gemm_core<128, 128, 64, 2, 2>(A, Wt, sA, sW, m0, n0, acc);
    int tid = threadIdx.x, wid = tid >> 6, lane = tid & 63, lm = lane & 15, quad = lane >> 4;
    int wm = wid >> 1, wn = wid & 1;
#pragma unroll
    for (int mt = 0; mt < 4; ++mt)
#pragma unroll
        for (int nt = 0; nt < 4; ++nt) {
            int col = n0 + wn * 64 + nt * 16 + lm;
#pragma unroll
            for (int r = 0; r < 4; ++r) {
                int row = m0 + wm * 64 + mt * 16 + quad * 4 + r;
                Bu[row * 256 + col] = acc[mt][nt][r];
            }
        }
}

// k4: per-chunk local scan. Interleaved Bu -> one coalesced f32x2 load/step.
// Two-deep group double-buffer (16 loads in flight while chain runs).
// xsh TIME-MAJOR interleaved: xsh[t*256+2p] half2 -> coalesced 4B/lane stores.
__global__ __launch_bounds__(128, 4) void s5_k4_scan(const float* __restrict__ Bu,
                                                     const float* __restrict__ aR, const float* __restrict__ aI,
                                                     _Float16* __restrict__ xsh,
                                                     float* __restrict__ carRI) {
    int p = threadIdx.x, c = blockIdx.x;
    float ar = aR[p], ai = aI[p];
    int t0 = c * TCH;
    const float* bp = Bu + t0 * 256 + 2 * p;
    _Float16* xp = xsh + t0 * 256 + 2 * p;
    f32x2 b0[16], b1[16];
    float sr = 0.f, si = 0.f;

    auto loadg = [&](f32x2 (&buf)[16], int g) {
#pragma unroll
        for (int j = 0; j < 16; ++j) buf[j] = *(const f32x2*)(bp + (g * 16 + j) * 256);
    };
    auto procg = [&](f32x2 (&buf)[16], int g) {
#pragma unroll
        for (int j = 0; j < 16; ++j) {
            float nr = fmaf(ar, sr, fmaf(-ai, si, buf[j][0]));
            float ni = fmaf(ar, si, fmaf(ai, sr, buf[j][1]));
            sr = nr; si = ni;
            *(half2v*)(xp + (g * 16 + j) * 256) = half2v{(_Float16)sr, (_Float16)si};
        }
    };
    loadg(b0, 0);
    loadg(b1, 1);
    procg(b0, 0);
    loadg(b0, 2);
    procg(b1, 1);
    loadg(b1, 3);
    procg(b0, 2);
    procg(b1, 3);
    *(f32x2*)(carRI + (c * 128 + p) * 2) = f32x2{sr, si};
}

// k6: applies carry. Preloads whole chunk as 64 coalesced half2 (static full
// unroll -> registers), own exclusive carry-prefix (unroll 8, L2-resident),
// coalesced half2 stores to xs2.
__global__ __launch_bounds__(128, 4) void s5_k6_apply(const _Float16* __restrict__ xsh,
                                                      const float* __restrict__ carRI,
                                                      const float* __restrict__ aR, const float* __restrict__ aI,
                                                      const float* __restrict__ aTR, const float* __restrict__ aTI,
                                                      _Float16* __restrict__ xs2) {
    int p = threadIdx.x, c = blockIdx.x;
    int t0 = c * TCH;
    const _Float16* xp = xsh + t0 * 256 + 2 * p;
    half2v hv[TCH];
#pragma unroll
    for (int j = 0; j < TCH; ++j) hv[j] = *(const half2v*)(xp + j * 256);
    float tr = aTR[p], ti = aTI[p];
    float cr = 0.f, ci = 0.f;
#pragma unroll 8
    for (int i = 0; i < c; ++i) {                 // exclusive prefix over chunks 0..c-1
        f32x2 w = *(const f32x2*)(carRI + (i * 128 + p) * 2);
        float nr = fmaf(tr, cr, fmaf(-ti, ci, w[0]));
        float ni = fmaf(tr, ci, fmaf(ti, cr, w[1]));
        cr = nr; ci = ni;
    }
    float ar = aR[p], ai = aI[p];
    float fr = ar, fi = ai;       // a^(j+1)
    _Float16* op = xs2 + t0 * 256 + 2 * p;
#pragma unroll
    for (int j = 0; j < TCH; ++j) {
        float xr = (float)hv[j][0] + fr * cr - fi * ci;
        float xi = (float)hv[j][1] + fr * ci + fi * cr;
        *(half2v*)(op + j * 256) = half2v{(_Float16)xr, (_Float16)xi};
        float nr = fr * ar - fi * ai, ni = fr * ai + fi * ar;
        fr = nr; fi = ni;
    }
}

__global__ __launch_bounds__(256) void s5_k7_gemm_c(const _Float16* __restrict__ A,
                                                    const _Float16* __restrict__ Wt,
                                                    const _Float16* __restrict__ h,
                                                    const float* __restrict__ Dv,
                                                    const float* __restrict__ gamma,
                                                    const float* __restrict__ beta,
                                                    _Float16* __restrict__ g) {
    __shared__ _Float16 sA[2 * 4 * 512], sW[2 * 16 * 512];
    __shared__ float red1[64][4], red2[64][4], mu_s[64], rs_s[64];
    f32x4 acc[4][4];
    int m0 = blockIdx.x * 64;
    gemm_core<64, 256, 32, 1, 4>(A, Wt, sA, sW, m0, 0, acc);
    int tid = threadIdx.x, wid = tid >> 6, lane = tid & 63, lm = lane & 15, quad = lane >> 4;
    int wn = wid;
    // y = xs@Wc + h*D
#pragma unroll
    for (int nt = 0; nt < 4; ++nt) {
        int col = wn * 64 + nt * 16 + lm;
        float dv = Dv[col];
#pragma unroll
        for (int mt = 0; mt < 4; ++mt)
#pragma unroll
            for (int r = 0; r < 4; ++r) {
                int row = m0 + mt * 16 + quad * 4 + r;
                acc[mt][nt][r] += (float)h[row * 256 + col] * dv;
            }
    }
    // row stats (LN over 256 cols spread over 4 waves x 4 nt x 16 lanes)
    float s1[4][4], s2[4][4];
#pragma unroll
    for (int mt = 0; mt < 4; ++mt)
#pragma unroll
        for (int r = 0; r < 4; ++r) {
            float a = 0.f, b = 0.f;
#pragma unroll
            for (int nt = 0; nt < 4; ++nt) {
                float v = acc[mt][nt][r];
                a += v; b += v * v;
            }
#pragma unroll
            for (int off = 1; off < 16; off <<= 1) {
                a += __shfl_xor(a, off, 64);
                b += __shfl_xor(b, off, 64);
            }
            s1[mt][r] = a; s2[mt][r] = b;
        }
    if (lm == 0) {
#pragma unroll
        for (int mt = 0; mt < 4; ++mt)
#pragma unroll
            for (int r = 0; r < 4; ++r) {
                int row = mt * 16 + quad * 4 + r;
                red1[row][wid] = s1[mt][r];
                red2[row][wid] = s2[mt][r];
            }
    }
    __syncthreads();
    if (tid < 64) {
        float a = red1[tid][0] + red1[tid][1] + red1[tid][2] + red1[tid][3];
        float b = red2[tid][0] + red2[tid][1] + red2[tid][2] + red2[tid][3];
        float mu = a * (1.f / 256.f);
        float var = b * (1.f / 256.f) - mu * mu;
        mu_s[tid] = mu;
        rs_s[tid] = rsqrtf(fmaxf(var, 0.f) + 1e-6f);
    }
    __syncthreads();
#pragma unroll
    for (int nt = 0; nt < 4; ++nt) {
        int col = wn * 64 + nt * 16 + lm;
        float ga = gamma[col], be = beta[col];
#pragma unroll
        for (int mt = 0; mt < 4; ++mt)
#pragma unroll
            for (int r = 0; r < 4; ++r) {
                int rl = mt * 16 + quad * 4 + r;
                float hn = (acc[mt][nt][r] - mu_s[rl]) * rs_s[rl] * ga + be;
                g[(m0 + rl) * 256 + col] = (_Float16)gelu_(hn);
            }
    }
}

// k8 v2: register-streaming GEMM. W-tile (128 cols x 256 K = 64KB) preloaded to
// LDS ONCE (single barrier); each wave then independently streams A-fragments
// global->VGPR (16 rows x 64B full cache lines, perfectly coalesced) with a
// 2-deep pipelined af buffer prefetching across ks and across m-tiles.
// ZERO barriers / cross-wave deps in the main loop. Each block: 2 tiles of
// 128 rows; wave owns 32 rows x all 128 cols (acc[2][8] = 64 VGPR).
__global__ __launch_bounds__(256) void s5_k8_gemm_glu(const _Float16* __restrict__ A,
                                                      const _Float16* __restrict__ Wt,
                                                      const float* __restrict__ bias,
                                                      float* __restrict__ x,
                                                      _Float16* __restrict__ xh) {
    __shared__ _Float16 sW[64 * 512];        // fragment-major: chunk c = ks*8 + n16
    int tid = threadIdx.x, wid = tid >> 6, lane = tid & 63;
    int lm = lane & 15, quad = lane >> 4;
    int n0 = blockIdx.y * 128;
    int m0 = blockIdx.x * 256;
    // one-time W preload: 64 chunks, 16 per wave
#pragma unroll
    for (int i = 0; i < 16; ++i) {
        int c = i * 4 + wid;
        int ks = c >> 3, n16 = c & 7;
        const _Float16* gp = Wt + (n0 + n16 * 16 + lm) * 256 + ks * 32 + quad * 8;
        gll16(gp, sW + c * 512);
    }
    asm volatile("s_waitcnt vmcnt(0)" ::: "memory");
    __syncthreads();

    f32x4 zero = {0.f, 0.f, 0.f, 0.f};
    half8 af[2][2];
    {   // preload tile0 ks=0
        int rowb = m0 + wid * 32;
#pragma unroll
        for (int mt = 0; mt < 2; ++mt)
            af[0][mt] = *(const half8*)(A + (rowb + mt * 16 + lm) * 256 + quad * 8);
    }
#pragma unroll
    for (int it = 0; it < 2; ++it) {
        int rowb = m0 + it * 128 + wid * 32;
        f32x4 acc[2][8];
#pragma unroll
        for (int mt = 0; mt < 2; ++mt)
#pragma unroll
            for (int nt = 0; nt < 8; ++nt) acc[mt][nt] = zero;
#pragma unroll
        for (int ks = 0; ks < 8; ++ks) {
            const int cur = ks & 1, nxt = cur ^ 1;
            // prefetch: same-tile ks+1, or next tile's ks=0 (lands in af[0] ✓)
            if (ks < 7) {
#pragma unroll
                for (int mt = 0; mt < 2; ++mt)
                    af[nxt][mt] = *(const half8*)(A + (rowb + mt * 16 + lm) * 256 + (ks + 1) * 32 + quad * 8);
            } else if (it == 0) {
#pragma unroll
                for (int mt = 0; mt < 2; ++mt)
                    af[nxt][mt] = *(const half8*)(A + (rowb + 128 + mt * 16 + lm) * 256 + quad * 8);
            }
            half8 bf[8];
#pragma unroll
            for (int nt = 0; nt < 8; ++nt)
                bf[nt] = *(const half8*)(sW + (ks * 8 + nt) * 512 + lane * 8);
#pragma unroll
            for (int mt = 0; mt < 2; ++mt)
#pragma unroll
                for (int nt = 0; nt < 8; ++nt)
                    acc[mt][nt] = __builtin_amdgcn_mfma_f32_16x16x32_f16(af[cur][mt], bf[nt], acc[mt][nt], 0, 0, 0);
        }
        // epilogue: in-thread GLU pairs (nt=2q, 2q+1), coalesced RMW on x
        int jbase = (n0 >> 1) + lm;
#pragma unroll
        for (int mt = 0; mt < 2; ++mt)
#pragma unroll
            for (int q = 0; q < 4; ++q) {
                float b1v = bias[n0 + (2 * q) * 16 + lm];
                float b2v = bias[n0 + (2 * q + 1) * 16 + lm];
                int jcol = jbase + q * 16;
#pragma unroll
                for (int r = 0; r < 4; ++r) {
                    float u1 = acc[mt][2 * q][r] + b1v;
                    float u2 = acc[mt][2 * q + 1][r] + b2v;
                    float gl = u1 * sigmoidf_(u2);
                    int row = rowb + mt * 16 + quad * 4 + r;
                    int idx = row * 256 + jcol;
                    float xn = x[idx] + gl;          // residual
                    x[idx] = xn;
                    xh[idx] = (_Float16)xn;
                }
            }
    }
}

__global__ __launch_bounds__(256) void s5_k9_gemm_out(const _Float16* __restrict__ A,
                                                      const _Float16* __restrict__ Wt,
                                                      const float* __restrict__ bout,
                                                      float* __restrict__ out) {
    __shared__ _Float16 sA[2 * 16 * 512], sW[2 * 8 * 512];
    f32x4 acc[2][4];
    int m0 = blockIdx.x * 128;
    gemm_core<128, 64, 64, 4, 1>(A, Wt, sA, sW, m0, 0, acc);
    int tid = threadIdx.x, wid = tid >> 6, lane = tid & 63, lm = lane & 15, quad = lane >> 4;
#pragma unroll
    for (int mt = 0; mt < 2; ++mt)
#pragma unroll
        for (int nt = 0; nt < 4; ++nt) {
            int col = nt * 16 + lm;
            float bv = bout[col];
#pragma unroll
            for (int r = 0; r < 4; ++r) {
                int row = m0 + wid * 32 + mt * 16 + quad * 4 + r;
                out[row * 64 + col] = acc[mt][nt][r] + bv;
            }
        }
}

// --------------------------- workspace layout ------------------------------
constexpr size_t OFF_X    = 0;                         // fp32 L*256      33.6MB
constexpr size_t OFF_BU   = 33554432;                  // fp32 L*256 (reused: xs2 half + g half)
constexpr size_t OFF_H    = 67108864;                  // half L*256 (h; reused as xh)
constexpr size_t OFF_XSH  = 83886080;                  // half L*256 (local scans, time-major)
constexpr size_t OFF_WBU  = 100663296;                 // half 4*256*256
constexpr size_t OFF_WC   = OFF_WBU + 524288;
constexpr size_t OFF_WGLU = OFF_WC + 524288;           // half 4*512*256
constexpr size_t OFF_WOUT = OFF_WGLU + 1048576;        // half 64*256
constexpr size_t OFF_BGLU = OFF_WOUT + 32768;          // f32 4*512
constexpr size_t OFF_AR   = OFF_BGLU + 8192;
constexpr size_t OFF_AI   = OFF_AR + 2048;
constexpr size_t OFF_CBR  = OFF_AI + 2048;
constexpr size_t OFF_CBI  = OFF_CBR + 2048;
constexpr size_t OFF_ATR  = OFF_CBI + 2048;
constexpr size_t OFF_ATI  = OFF_ATR + 2048;
constexpr size_t OFF_ALP  = OFF_ATI + 2048;
constexpr size_t OFF_RALP = OFF_ALP + 2048;
constexpr size_t OFF_X0   = OFF_RALP + 2048;
constexpr size_t OFF_CARRI= OFF_X0 + 1024;             // f32x2 NCH*128 (512KB)

extern "C" void kernel_launch(void* const* d_in, const int* in_sizes, int n_in,
                              void* d_out, int out_size, void* d_ws, size_t ws_size,
                              hipStream_t stream) {
    (void)in_sizes; (void)n_in; (void)out_size; (void)ws_size;
    const float* latent    = (const float*)d_in[0];
    const float* W_expand  = (const float*)d_in[1];
    const float* b_expand  = (const float*)d_in[2];
    const float* norm_s    = (const float*)d_in[3];
    const float* norm_b    = (const float*)d_in[4];
    const float* Lre       = (const float*)d_in[5];
    const float* Lim       = (const float*)d_in[6];
    const float* Bre       = (const float*)d_in[7];
    const float* Bim       = (const float*)d_in[8];
    const float* Cre       = (const float*)d_in[9];
    const float* Cim       = (const float*)d_in[10];
    const float* Dv        = (const float*)d_in[11];
    const float* lstep     = (const float*)d_in[12];
    const float* W1        = (const float*)d_in[13];
    const float* b1        = (const float*)d_in[14];
    const float* W2        = (const float*)d_in[15];
    const float* b2        = (const float*)d_in[16];
    const float* Wout      = (const float*)d_in[17];
    const float* bout      = (const float*)d_in[18];

    char* ws = (char*)d_ws;
    float*    x    = (float*)(ws + OFF_X);
    float*    Bu   = (float*)(ws + OFF_BU);
    _Float16* xs2  = (_Float16*)(ws + OFF_BU);                 // after k4, Bu region is free
    _Float16* gbuf = (_Float16*)(ws + OFF_BU + 16777216);
    _Float16* hbuf = (_Float16*)(ws + OFF_H);
    _Float16* xh   = (_Float16*)(ws + OFF_H);                  // h dead once k8 runs
    _Float16* xsh  = (_Float16*)(ws + OFF_XSH);
    _Float16* Wbu  = (_Float16*)(ws + OFF_WBU);
    _Float16* Wc   = (_Float16*)(ws + OFF_WC);
    _Float16* Wglu = (_Float16*)(ws + OFF_WGLU);
    _Float16* WoutT= (_Float16*)(ws + OFF_WOUT);
    float* bglu = (float*)(ws + OFF_BGLU);
    float* aR  = (float*)(ws + OFF_AR);
    float* aI  = (float*)(ws + OFF_AI);
    float* cbR = (float*)(ws + OFF_CBR);
    float* cbI = (float*)(ws + OFF_CBI);
    float* aTR = (float*)(ws + OFF_ATR);
    float* aTI = (float*)(ws + OFF_ATI);
    float* alp = (float*)(ws + OFF_ALP);
    float* ralp= (float*)(ws + OFF_RALP);
    float* x0  = (float*)(ws + OFF_X0);
    float* carRI=(float*)(ws + OFF_CARRI);

    s5_k0a<<<1, 512, 0, stream>>>(Lre, Lim, lstep, aR, aI, cbR, cbI, aTR, aTI, alp, ralp);
    s5_k0b<<<256, 256, 0, stream>>>(Bre, Bim, Cre, Cim, W1, W2, b1, b2, Wout,
                                    cbR, cbI, alp, ralp, Wbu, Wc, Wglu, WoutT, bglu);
    s5_k0c<<<1, 256, 0, stream>>>(latent, W_expand, b_expand, x0);
    s5_k1_fill<<<8192, 256, 0, stream>>>(x0, x);

    for (int l = 0; l < 4; ++l) {
        s5_k2_ln<<<8192, 256, 0, stream>>>(x, norm_s + l * 256, norm_b + l * 256, hbuf);
        s5_k3_gemm_bu<<<dim3(256, 2), 256, 0, stream>>>(hbuf, Wbu + l * 65536, Bu);
        s5_k4_scan<<<NCH, 128, 0, stream>>>(Bu, aR + l * 128, aI + l * 128, xsh, carRI);
        s5_k6_apply<<<NCH, 128, 0, stream>>>(xsh, carRI, aR + l * 128, aI + l * 128,
                                             aTR + l * 128, aTI + l * 128, xs2);
        s5_k7_gemm_c<<<512, 256, 0, stream>>>(xs2, Wc + l * 65536, hbuf, Dv + l * 256,
                                              norm_s + l * 256, norm_b + l * 256, gbuf);
        s5_k8_gemm_glu<<<dim3(128, 4), 256, 0, stream>>>(gbuf, Wglu + l * 131072,
                                                         bglu + l * 512, x, xh);
    }
    s5_k9_gemm_out<<<256, 256, 0, stream>>>(xh, WoutT, bout, (float*)d_out);
}

// Round 7
// 577.568 us; speedup vs baseline: 1.8564x; 1.1126x over previous
//
#include <hip/hip_runtime.h>
#include <stdint.h>

#define LSEQ 32768
#define NCH 512      // scan chunks
#define TCH 64       // timesteps per chunk  (NCH*TCH == LSEQ)

typedef _Float16 half8 __attribute__((ext_vector_type(8)));
typedef _Float16 half4v __attribute__((ext_vector_type(4)));
typedef _Float16 half2v __attribute__((ext_vector_type(2)));
typedef float f32x4 __attribute__((ext_vector_type(4)));
typedef float f32x2 __attribute__((ext_vector_type(2)));

__device__ __forceinline__ float sigmoidf_(float x) { return 1.f / (1.f + __expf(-x)); }
__device__ __forceinline__ float gelu_(float x) {
    float z = 0.7978845608028654f * (x + 0.044715f * x * x * x);
    float e = __expf(2.f * z);
    float t = 1.f - 2.f / (e + 1.f);   // tanh(z)
    return 0.5f * x * (1.f + t);
}

// async global->LDS, 16B per lane. LDS dest is wave-uniform base; HW writes
// base + lane*16 (matches the fragment-major chunk layout below).
__device__ __forceinline__ void gll16(const _Float16* gp, _Float16* lp) {
    __builtin_amdgcn_global_load_lds((__attribute__((address_space(1))) void*)gp,
                                     (__attribute__((address_space(3))) void*)lp, 16, 0, 0);
}

// ---------------------------------------------------------------------------
// old barrier-per-K-step core; still used by k9 (small, not hot)
// ---------------------------------------------------------------------------
template <int BM, int BN, int BK, int WR, int WC>
__device__ __forceinline__ void gemm_core(const _Float16* __restrict__ A,
                                          const _Float16* __restrict__ Wt,
                                          _Float16* sA, _Float16* sW,
                                          int m0, int n0,
                                          f32x4 (&acc)[BM / (WR * 16)][BN / (WC * 16)]) {
    constexpr int MT = BM / (WR * 16);
    constexpr int NT = BN / (WC * 16);
    constexpr int KS = BK / 32;
    constexpr int CA = KS * (BM / 16);
    constexpr int CW = KS * (BN / 16);
    constexpr int NKB = 256 / BK;
    constexpr int NWAVE = WR * WC;
    const int tid = threadIdx.x;
    const int wid = tid >> 6;
    const int lane = tid & 63;
    const int wm = wid / WC;
    const int wn = wid % WC;

    f32x4 zero = {0.f, 0.f, 0.f, 0.f};
#pragma unroll
    for (int i = 0; i < MT; ++i)
#pragma unroll
        for (int j = 0; j < NT; ++j) acc[i][j] = zero;

    auto stage = [&](int kb, int buf) {
#pragma unroll
        for (int i = 0; i < CA / NWAVE; ++i) {
            int c = i * NWAVE + wid;
            int ks = c / (BM / 16), r16 = c % (BM / 16);
            const _Float16* gp = A + (m0 + r16 * 16 + (lane & 15)) * 256 + kb + ks * 32 + (lane >> 4) * 8;
            gll16(gp, sA + buf * (CA * 512) + c * 512);
        }
#pragma unroll
        for (int i = 0; i < CW / NWAVE; ++i) {
            int c = i * NWAVE + wid;
            int ks = c / (BN / 16), n16 = c % (BN / 16);
            const _Float16* gp = Wt + (n0 + n16 * 16 + (lane & 15)) * 256 + kb + ks * 32 + (lane >> 4) * 8;
            gll16(gp, sW + buf * (CW * 512) + c * 512);
        }
    };

    stage(0, 0);
#pragma unroll
    for (int t = 0; t < NKB; ++t) {
        __syncthreads();
        if (t + 1 < NKB) stage((t + 1) * BK, (t + 1) & 1);
        const _Float16* bA = sA + (t & 1) * (CA * 512);
        const _Float16* bW = sW + (t & 1) * (CW * 512);
#pragma unroll
        for (int ks = 0; ks < KS; ++ks) {
            half8 af[MT], bf[NT];
#pragma unroll
            for (int mt = 0; mt < MT; ++mt)
                af[mt] = *(const half8*)(bA + (ks * (BM / 16) + wm * MT + mt) * 512 + lane * 8);
#pragma unroll
            for (int nt = 0; nt < NT; ++nt)
                bf[nt] = *(const half8*)(bW + (ks * (BN / 16) + wn * NT + nt) * 512 + lane * 8);
#pragma unroll
            for (int mt = 0; mt < MT; ++mt)
#pragma unroll
                for (int nt = 0; nt < NT; ++nt)
                    acc[mt][nt] = __builtin_amdgcn_mfma_f32_16x16x32_f16(af[mt], bf[nt], acc[mt][nt], 0, 0, 0);
        }
    }
    __syncthreads();
}

// --------------------------- setup kernels ---------------------------------
__global__ __launch_bounds__(512) void s5_k0a(const float* __restrict__ lre, const float* __restrict__ lim,
                                              const float* __restrict__ lstep,
                                              float* aR, float* aI, float* cbR, float* cbI,
                                              float* aTR, float* aTI, float* alp, float* ralp) {
    int i = threadIdx.x;  // 4 layers * 128 channels
    float st = expf(lstep[i]);
    float lr = lre[i] * st, li = lim[i] * st;
    float ea = expf(lr);
    float ar = ea * cosf(li), ai = ea * sinf(li);
    float den = lre[i] * lre[i] + lim[i] * lim[i];
    float nr = ar - 1.f, ni = ai;
    float cr = (nr * lre[i] + ni * lim[i]) / den;   // (a-1)/Lambda
    float ci = (ni * lre[i] - nr * lim[i]) / den;
    float cm = sqrtf(cr * cr + ci * ci);
    float al = sqrtf(2.83f / fmaxf(cm, 1e-8f));    // fp16 dynamic-range balancing
    float eT = expf(lr * (float)TCH);
    aR[i] = ar; aI[i] = ai;
    cbR[i] = cr; cbI[i] = ci;
    aTR[i] = eT * cosf(li * (float)TCH);
    aTI[i] = eT * sinf(li * (float)TCH);
    alp[i] = al; ralp[i] = 1.f / al;
}

__global__ __launch_bounds__(256) void s5_k0b(const float* __restrict__ Bre, const float* __restrict__ Bim,
                                              const float* __restrict__ Cre, const float* __restrict__ Cim,
                                              const float* __restrict__ W1, const float* __restrict__ W2,
                                              const float* __restrict__ b1, const float* __restrict__ b2,
                                              const float* __restrict__ Wout,
                                              const float* __restrict__ cbR, const float* __restrict__ cbI,
                                              const float* __restrict__ alp, const float* __restrict__ ralp,
                                              _Float16* Wbu, _Float16* Wc, _Float16* Wglu,
                                              _Float16* WoutT, float* bglu) {
    int stride = gridDim.x * blockDim.x;
    int tid0 = blockIdx.x * blockDim.x + threadIdx.x;
    // Wbu_t[l][n][k]: channels INTERLEAVED: n=2p -> re(Bbar_p), n=2p+1 -> im(Bbar_p);
    // scaled by alpha[p]. k3 then writes Bu[t][2p,2p+1] = (re,im) naturally.
    for (int i = tid0; i < 262144; i += stride) {
        int l = i >> 16, n = (i >> 8) & 255, k = i & 255;
        int p = l * 128 + (n >> 1);
        float re = cbR[p] * Bre[p * 256 + k] - cbI[p] * Bim[p * 256 + k];
        float im = cbR[p] * Bim[p * 256 + k] + cbI[p] * Bre[p * 256 + k];
        Wbu[i] = (_Float16)(((n & 1) ? im : re) * alp[p]);
    }
    // Wc_t[l][n][k]: k-axis interleaved to match xs2: k=2p -> 2*Cre[n][p],
    // k=2p+1 -> -2*Cim[n][p]; scaled by 1/alpha[p]
    for (int i = tid0; i < 262144; i += stride) {
        int l = i >> 16, n = (i >> 8) & 255, k = i & 255;
        int p = k >> 1;
        float base = (k & 1) ? -2.f * Cim[(l * 256 + n) * 128 + p]
                             : 2.f * Cre[(l * 256 + n) * 128 + p];
        Wc[i] = (_Float16)(base * ralp[l * 128 + p]);
    }
    // Wglu_t[l][n][k]: columns permuted so GLU pairs land in the SAME thread.
    for (int i = tid0; i < 524288; i += stride) {
        int l = i >> 17, n = (i >> 8) & 511, k = i & 255;
        int j = ((n >> 7) << 6) | (((n >> 6) & 1) << 5) | (((n >> 5) & 1) << 4) | (n & 15);
        const float* src = ((n >> 4) & 1) ? W2 : W1;
        Wglu[i] = (_Float16)src[(l * 256 + k) * 256 + j];
    }
    for (int i = tid0; i < 16384; i += stride) {
        int n = i >> 8, k = i & 255;
        WoutT[i] = (_Float16)Wout[k * 64 + n];
    }
    for (int i = tid0; i < 2048; i += stride) {
        int l = i >> 9, n = i & 511;
        int j = ((n >> 7) << 6) | (((n >> 6) & 1) << 5) | (((n >> 5) & 1) << 4) | (n & 15);
        bglu[i] = (((n >> 4) & 1) ? b2 : b1)[l * 256 + j];
    }
}

__global__ __launch_bounds__(256) void s5_k0c(const float* __restrict__ latent, const float* __restrict__ W,
                                              const float* __restrict__ b, float* __restrict__ x0) {
    __shared__ float lat[256];
    lat[threadIdx.x] = latent[threadIdx.x];
    __syncthreads();
    float s = b[threadIdx.x];
    for (int k = 0; k < 256; ++k) s += lat[k] * W[k * 256 + threadIdx.x];
    x0[threadIdx.x] = (s > 0.f) ? s : 0.01f * s;   // leaky_relu
}

__global__ __launch_bounds__(256) void s5_k1_fill(const float* __restrict__ x0, float* __restrict__ x) {
    int i = blockIdx.x * 256 + threadIdx.x;       // 8192 blocks: L*256/4 float4s
    f32x4 v = *(const f32x4*)(x0 + (i & 63) * 4);
    *(f32x4*)(x + i * 4) = v;
}

// --------------------------- per-layer kernels -----------------------------
__global__ __launch_bounds__(256) void s5_k2_ln(const float* __restrict__ x, const float* __restrict__ gamma,
                                                const float* __restrict__ beta, _Float16* __restrict__ h) {
    int wid = threadIdx.x >> 6, lane = threadIdx.x & 63;
    int row = blockIdx.x * 4 + wid;
    const float* xr = x + row * 256;
    f32x4 v = *(const f32x4*)(xr + lane * 4);
    float s1 = v[0] + v[1] + v[2] + v[3];
    float s2 = v[0] * v[0] + v[1] * v[1] + v[2] * v[2] + v[3] * v[3];
#pragma unroll
    for (int off = 1; off < 64; off <<= 1) {
        s1 += __shfl_xor(s1, off, 64);
        s2 += __shfl_xor(s2, off, 64);
    }
    float mu = s1 * (1.f / 256.f);
    float var = s2 * (1.f / 256.f) - mu * mu;
    float rs = rsqrtf(fmaxf(var, 0.f) + 1e-6f);
    f32x4 g4 = *(const f32x4*)(gamma + lane * 4);
    f32x4 b4 = *(const f32x4*)(beta + lane * 4);
    half4v o;
#pragma unroll
    for (int j = 0; j < 4; ++j) o[j] = (_Float16)((v[j] - mu) * rs * g4[j] + b4[j]);
    *(half4v*)(h + row * 256 + lane * 4) = o;
}

// k3 v3: deep-MLP streaming GEMM. W-tile (128x256, 64KB) -> LDS once; each
// wave preloads its ENTIRE 32-row A-tile (16x16B loads/thread, 64 VGPR, all
// outstanding at once -- the k6 recipe), then runs all 128 MFMAs. No main-loop
// barriers. Wave owns 32 rows x 128 cols.
__global__ __launch_bounds__(256, 2) void s5_k3_gemm_bu(const _Float16* __restrict__ A,
                                                        const _Float16* __restrict__ Wt,
                                                        float* __restrict__ Bu) {
    __shared__ _Float16 sW[64 * 512];        // chunk c = ks*8 + n16
    int tid = threadIdx.x, wid = tid >> 6, lane = tid & 63;
    int lm = lane & 15, quad = lane >> 4;
    int m0 = blockIdx.x * 128, n0 = blockIdx.y * 128;
#pragma unroll
    for (int i = 0; i < 16; ++i) {
        int c = i * 4 + wid;
        int ks = c >> 3, n16 = c & 7;
        gll16(Wt + (n0 + n16 * 16 + lm) * 256 + ks * 32 + quad * 8, sW + c * 512);
    }
    int rowb = m0 + wid * 32;
    half8 af[2][8];
#pragma unroll
    for (int mt = 0; mt < 2; ++mt)
#pragma unroll
        for (int ks = 0; ks < 8; ++ks)
            af[mt][ks] = *(const half8*)(A + (rowb + mt * 16 + lm) * 256 + ks * 32 + quad * 8);
    asm volatile("s_waitcnt vmcnt(0)" ::: "memory");
    __syncthreads();

    f32x4 zero = {0.f, 0.f, 0.f, 0.f};
    f32x4 acc[2][8];
#pragma unroll
    for (int mt = 0; mt < 2; ++mt)
#pragma unroll
        for (int nt = 0; nt < 8; ++nt) acc[mt][nt] = zero;
#pragma unroll
    for (int ks = 0; ks < 8; ++ks) {
        half8 bf[8];
#pragma unroll
        for (int nt = 0; nt < 8; ++nt)
            bf[nt] = *(const half8*)(sW + (ks * 8 + nt) * 512 + lane * 8);
#pragma unroll
        for (int mt = 0; mt < 2; ++mt)
#pragma unroll
            for (int nt = 0; nt < 8; ++nt)
                acc[mt][nt] = __builtin_amdgcn_mfma_f32_16x16x32_f16(af[mt][ks], bf[nt], acc[mt][nt], 0, 0, 0);
    }
#pragma unroll
    for (int mt = 0; mt < 2; ++mt)
#pragma unroll
        for (int nt = 0; nt < 8; ++nt) {
            int col = n0 + nt * 16 + lm;
#pragma unroll
            for (int r = 0; r < 4; ++r)
                Bu[(rowb + mt * 16 + quad * 4 + r) * 256 + col] = acc[mt][nt][r];
        }
}

// k4: per-chunk local scan (deep-MLP, coalesced; unchanged from round 5)
__global__ __launch_bounds__(128, 4) void s5_k4_scan(const float* __restrict__ Bu,
                                                     const float* __restrict__ aR, const float* __restrict__ aI,
                                                     _Float16* __restrict__ xsh,
                                                     float* __restrict__ carRI) {
    int p = threadIdx.x, c = blockIdx.x;
    float ar = aR[p], ai = aI[p];
    int t0 = c * TCH;
    const float* bp = Bu + t0 * 256 + 2 * p;
    _Float16* xp = xsh + t0 * 256 + 2 * p;
    f32x2 b0[16], b1[16];
    float sr = 0.f, si = 0.f;

    auto loadg = [&](f32x2 (&buf)[16], int g) {
#pragma unroll
        for (int j = 0; j < 16; ++j) buf[j] = *(const f32x2*)(bp + (g * 16 + j) * 256);
    };
    auto procg = [&](f32x2 (&buf)[16], int g) {
#pragma unroll
        for (int j = 0; j < 16; ++j) {
            float nr = fmaf(ar, sr, fmaf(-ai, si, buf[j][0]));
            float ni = fmaf(ar, si, fmaf(ai, sr, buf[j][1]));
            sr = nr; si = ni;
            *(half2v*)(xp + (g * 16 + j) * 256) = half2v{(_Float16)sr, (_Float16)si};
        }
    };
    loadg(b0, 0);
    loadg(b1, 1);
    procg(b0, 0);
    loadg(b0, 2);
    procg(b1, 1);
    loadg(b1, 3);
    procg(b0, 2);
    procg(b1, 3);
    *(f32x2*)(carRI + (c * 128 + p) * 2) = f32x2{sr, si};
}

// k6: carry apply (deep-MLP preload; unchanged from round 5)
__global__ __launch_bounds__(128, 4) void s5_k6_apply(const _Float16* __restrict__ xsh,
                                                      const float* __restrict__ carRI,
                                                      const float* __restrict__ aR, const float* __restrict__ aI,
                                                      const float* __restrict__ aTR, const float* __restrict__ aTI,
                                                      _Float16* __restrict__ xs2) {
    int p = threadIdx.x, c = blockIdx.x;
    int t0 = c * TCH;
    const _Float16* xp = xsh + t0 * 256 + 2 * p;
    half2v hv[TCH];
#pragma unroll
    for (int j = 0; j < TCH; ++j) hv[j] = *(const half2v*)(xp + j * 256);
    float tr = aTR[p], ti = aTI[p];
    float cr = 0.f, ci = 0.f;
#pragma unroll 8
    for (int i = 0; i < c; ++i) {                 // exclusive prefix over chunks 0..c-1
        f32x2 w = *(const f32x2*)(carRI + (i * 128 + p) * 2);
        float nr = fmaf(tr, cr, fmaf(-ti, ci, w[0]));
        float ni = fmaf(tr, ci, fmaf(ti, cr, w[1]));
        cr = nr; ci = ni;
    }
    float ar = aR[p], ai = aI[p];
    float fr = ar, fi = ai;       // a^(j+1)
    _Float16* op = xs2 + t0 * 256 + 2 * p;
#pragma unroll
    for (int j = 0; j < TCH; ++j) {
        float xr = (float)hv[j][0] + fr * cr - fi * ci;
        float xi = (float)hv[j][1] + fr * ci + fi * cr;
        *(half2v*)(op + j * 256) = half2v{(_Float16)xr, (_Float16)xi};
        float nr = fr * ar - fi * ai, ni = fr * ai + fi * ar;
        fr = nr; fi = ni;
    }
}

// k7 v2: 512-thread/8-wave block; wave owns 16 rows x ALL 256 cols -> LN is
// wave-local (no LDS reduction, no epilogue barriers). W staged in two 64KB
// col-halves; A-tile preloaded ONCE to registers (8x16B/thread, deep MLP) and
// reused across both halves. grid=256 -> exactly 1 block/CU.
__global__ __launch_bounds__(512, 2) void s5_k7_gemm_c(const _Float16* __restrict__ A,
                                                       const _Float16* __restrict__ Wt,
                                                       const _Float16* __restrict__ h,
                                                       const float* __restrict__ Dv,
                                                       const float* __restrict__ gamma,
                                                       const float* __restrict__ beta,
                                                       _Float16* __restrict__ g) {
    __shared__ _Float16 sW[64 * 512];        // one col-half: chunk c = ks*8 + n16
    int tid = threadIdx.x, wid = tid >> 6, lane = tid & 63;
    int lm = lane & 15, quad = lane >> 4;
    int m0 = blockIdx.x * 128;
    int rowb = m0 + wid * 16;

    auto stageW = [&](int half) {
#pragma unroll
        for (int i = 0; i < 8; ++i) {
            int c = i * 8 + wid;
            int ks = c >> 3, n16 = c & 7;
            gll16(Wt + (half * 128 + n16 * 16 + lm) * 256 + ks * 32 + quad * 8, sW + c * 512);
        }
    };
    stageW(0);
    half8 af[8];
#pragma unroll
    for (int ks = 0; ks < 8; ++ks)
        af[ks] = *(const half8*)(A + (rowb + lm) * 256 + ks * 32 + quad * 8);
    asm volatile("s_waitcnt vmcnt(0)" ::: "memory");
    __syncthreads();

    f32x4 zero = {0.f, 0.f, 0.f, 0.f};
    f32x4 acc[2][8];
#pragma unroll
    for (int hf = 0; hf < 2; ++hf)
#pragma unroll
        for (int nt = 0; nt < 8; ++nt) acc[hf][nt] = zero;

#pragma unroll
    for (int ks = 0; ks < 8; ++ks) {
        half8 bf[8];
#pragma unroll
        for (int nt = 0; nt < 8; ++nt)
            bf[nt] = *(const half8*)(sW + (ks * 8 + nt) * 512 + lane * 8);
#pragma unroll
        for (int nt = 0; nt < 8; ++nt)
            acc[0][nt] = __builtin_amdgcn_mfma_f32_16x16x32_f16(af[ks], bf[nt], acc[0][nt], 0, 0, 0);
    }
    __syncthreads();                  // all waves done reading half 0
    stageW(1);
    asm volatile("s_waitcnt vmcnt(0)" ::: "memory");
    __syncthreads();
#pragma unroll
    for (int ks = 0; ks < 8; ++ks) {
        half8 bf[8];
#pragma unroll
        for (int nt = 0; nt < 8; ++nt)
            bf[nt] = *(const half8*)(sW + (ks * 8 + nt) * 512 + lane * 8);
#pragma unroll
        for (int nt = 0; nt < 8; ++nt)
            acc[1][nt] = __builtin_amdgcn_mfma_f32_16x16x32_f16(af[ks], bf[nt], acc[1][nt], 0, 0, 0);
    }

    // y = xs@Wc + h*D
#pragma unroll
    for (int hf = 0; hf < 2; ++hf)
#pragma unroll
        for (int nt = 0; nt < 8; ++nt) {
            int col = hf * 128 + nt * 16 + lm;
            float dv = Dv[col];
#pragma unroll
            for (int r = 0; r < 4; ++r)
                acc[hf][nt][r] += (float)h[(rowb + quad * 4 + r) * 256 + col] * dv;
        }
    // wave-local LN: row = rowb + quad*4 + r; sum over 16 nt in-thread,
    // then shfl over the 16 lm lanes (offsets 1,2,4,8 stay within quad group)
    float mu[4], rs[4];
#pragma unroll
    for (int r = 0; r < 4; ++r) {
        float a = 0.f, b = 0.f;
#pragma unroll
        for (int hf = 0; hf < 2; ++hf)
#pragma unroll
            for (int nt = 0; nt < 8; ++nt) {
                float v = acc[hf][nt][r];
                a += v; b += v * v;
            }
#pragma unroll
        for (int off = 1; off < 16; off <<= 1) {
            a += __shfl_xor(a, off, 64);
            b += __shfl_xor(b, off, 64);
        }
        float m = a * (1.f / 256.f);
        float var = b * (1.f / 256.f) - m * m;
        mu[r] = m;
        rs[r] = rsqrtf(fmaxf(var, 0.f) + 1e-6f);
    }
#pragma unroll
    for (int hf = 0; hf < 2; ++hf)
#pragma unroll
        for (int nt = 0; nt < 8; ++nt) {
            int col = hf * 128 + nt * 16 + lm;
            float ga = gamma[col], be = beta[col];
#pragma unroll
            for (int r = 0; r < 4; ++r) {
                float hn = (acc[hf][nt][r] - mu[r]) * rs[r] * ga + be;
                g[(rowb + quad * 4 + r) * 256 + col] = (_Float16)gelu_(hn);
            }
        }
}

// k8 v3: deep-MLP streaming GEMM + in-thread GLU epilogue with hoisted x loads.
__global__ __launch_bounds__(256, 2) void s5_k8_gemm_glu(const _Float16* __restrict__ A,
                                                         const _Float16* __restrict__ Wt,
                                                         const float* __restrict__ bias,
                                                         float* __restrict__ x,
                                                         _Float16* __restrict__ xh) {
    __shared__ _Float16 sW[64 * 512];        // chunk c = ks*8 + n16
    int tid = threadIdx.x, wid = tid >> 6, lane = tid & 63;
    int lm = lane & 15, quad = lane >> 4;
    int n0 = blockIdx.y * 128;
    int m0 = blockIdx.x * 128;
#pragma unroll
    for (int i = 0; i < 16; ++i) {
        int c = i * 4 + wid;
        int ks = c >> 3, n16 = c & 7;
        gll16(Wt + (n0 + n16 * 16 + lm) * 256 + ks * 32 + quad * 8, sW + c * 512);
    }
    int rowb = m0 + wid * 32;
    half8 af[2][8];
#pragma unroll
    for (int mt = 0; mt < 2; ++mt)
#pragma unroll
        for (int ks = 0; ks < 8; ++ks)
            af[mt][ks] = *(const half8*)(A + (rowb + mt * 16 + lm) * 256 + ks * 32 + quad * 8);
    asm volatile("s_waitcnt vmcnt(0)" ::: "memory");
    __syncthreads();

    f32x4 zero = {0.f, 0.f, 0.f, 0.f};
    f32x4 acc[2][8];
#pragma unroll
    for (int mt = 0; mt < 2; ++mt)
#pragma unroll
        for (int nt = 0; nt < 8; ++nt) acc[mt][nt] = zero;
#pragma unroll
    for (int ks = 0; ks < 8; ++ks) {
        half8 bf[8];
#pragma unroll
        for (int nt = 0; nt < 8; ++nt)
            bf[nt] = *(const half8*)(sW + (ks * 8 + nt) * 512 + lane * 8);
#pragma unroll
        for (int mt = 0; mt < 2; ++mt)
#pragma unroll
            for (int nt = 0; nt < 8; ++nt)
                acc[mt][nt] = __builtin_amdgcn_mfma_f32_16x16x32_f16(af[mt][ks], bf[nt], acc[mt][nt], 0, 0, 0);
    }
    // epilogue: hoist ALL x loads (32 independent, deep MLP), then GLU+store
    int jbase = (n0 >> 1) + lm;
    float xold[2][4][4];
#pragma unroll
    for (int mt = 0; mt < 2; ++mt)
#pragma unroll
        for (int q = 0; q < 4; ++q)
#pragma unroll
            for (int r = 0; r < 4; ++r)
                xold[mt][q][r] = x[(rowb + mt * 16 + quad * 4 + r) * 256 + jbase + q * 16];
#pragma unroll
    for (int mt = 0; mt < 2; ++mt)
#pragma unroll
        for (int q = 0; q < 4; ++q) {
            float b1v = bias[n0 + (2 * q) * 16 + lm];
            float b2v = bias[n0 + (2 * q + 1) * 16 + lm];
            int jcol = jbase + q * 16;
#pragma unroll
            for (int r = 0; r < 4; ++r) {
                float u1 = acc[mt][2 * q][r] + b1v;
                float u2 = acc[mt][2 * q + 1][r] + b2v;
                float gl = u1 * sigmoidf_(u2);
                int idx = (rowb + mt * 16 + quad * 4 + r) * 256 + jcol;
                float xn = xold[mt][q][r] + gl;      // residual
                x[idx] = xn;
                xh[idx] = (_Float16)xn;
            }
        }
}

__global__ __launch_bounds__(256) void s5_k9_gemm_out(const _Float16* __restrict__ A,
                                                      const _Float16* __restrict__ Wt,
                                                      const float* __restrict__ bout,
                                                      float* __restrict__ out) {
    __shared__ _Float16 sA[2 * 16 * 512], sW[2 * 8 * 512];
    f32x4 acc[2][4];
    int m0 = blockIdx.x * 128;
    gemm_core<128, 64, 64, 4, 1>(A, Wt, sA, sW, m0, 0, acc);
    int tid = threadIdx.x, wid = tid >> 6, lane = tid & 63, lm = lane & 15, quad = lane >> 4;
#pragma unroll
    for (int mt = 0; mt < 2; ++mt)
#pragma unroll
        for (int nt = 0; nt < 4; ++nt) {
            int col = nt * 16 + lm;
            float bv = bout[col];
#pragma unroll
            for (int r = 0; r < 4; ++r) {
                int row = m0 + wid * 32 + mt * 16 + quad * 4 + r;
                out[row * 64 + col] = acc[mt][nt][r] + bv;
            }
        }
}

// --------------------------- workspace layout ------------------------------
constexpr size_t OFF_X    = 0;                         // fp32 L*256      33.6MB
constexpr size_t OFF_BU   = 33554432;                  // fp32 L*256 (reused: xs2 half + g half)
constexpr size_t OFF_H    = 67108864;                  // half L*256 (h; reused as xh)
constexpr size_t OFF_XSH  = 83886080;                  // half L*256 (local scans, time-major)
constexpr size_t OFF_WBU  = 100663296;                 // half 4*256*256
constexpr size_t OFF_WC   = OFF_WBU + 524288;
constexpr size_t OFF_WGLU = OFF_WC + 524288;           // half 4*512*256
constexpr size_t OFF_WOUT = OFF_WGLU + 1048576;        // half 64*256
constexpr size_t OFF_BGLU = OFF_WOUT + 32768;          // f32 4*512
constexpr size_t OFF_AR   = OFF_BGLU + 8192;
constexpr size_t OFF_AI   = OFF_AR + 2048;
constexpr size_t OFF_CBR  = OFF_AI + 2048;
constexpr size_t OFF_CBI  = OFF_CBR + 2048;
constexpr size_t OFF_ATR  = OFF_CBI + 2048;
constexpr size_t OFF_ATI  = OFF_ATR + 2048;
constexpr size_t OFF_ALP  = OFF_ATI + 2048;
constexpr size_t OFF_RALP = OFF_ALP + 2048;
constexpr size_t OFF_X0   = OFF_RALP + 2048;
constexpr size_t OFF_CARRI= OFF_X0 + 1024;             // f32x2 NCH*128 (512KB)

extern "C" void kernel_launch(void* const* d_in, const int* in_sizes, int n_in,
                              void* d_out, int out_size, void* d_ws, size_t ws_size,
                              hipStream_t stream) {
    (void)in_sizes; (void)n_in; (void)out_size; (void)ws_size;
    const float* latent    = (const float*)d_in[0];
    const float* W_expand  = (const float*)d_in[1];
    const float* b_expand  = (const float*)d_in[2];
    const float* norm_s    = (const float*)d_in[3];
    const float* norm_b    = (const float*)d_in[4];
    const float* Lre       = (const float*)d_in[5];
    const float* Lim       = (const float*)d_in[6];
    const float* Bre       = (const float*)d_in[7];
    const float* Bim       = (const float*)d_in[8];
    const float* Cre       = (const float*)d_in[9];
    const float* Cim       = (const float*)d_in[10];
    const float* Dv        = (const float*)d_in[11];
    const float* lstep     = (const float*)d_in[12];
    const float* W1        = (const float*)d_in[13];
    const float* b1        = (const float*)d_in[14];
    const float* W2        = (const float*)d_in[15];
    const float* b2        = (const float*)d_in[16];
    const float* Wout      = (const float*)d_in[17];
    const float* bout      = (const float*)d_in[18];

    char* ws = (char*)d_ws;
    float*    x    = (float*)(ws + OFF_X);
    float*    Bu   = (float*)(ws + OFF_BU);
    _Float16* xs2  = (_Float16*)(ws + OFF_BU);                 // after k4, Bu region is free
    _Float16* gbuf = (_Float16*)(ws + OFF_BU + 16777216);
    _Float16* hbuf = (_Float16*)(ws + OFF_H);
    _Float16* xh   = (_Float16*)(ws + OFF_H);                  // h dead once k8 runs
    _Float16* xsh  = (_Float16*)(ws + OFF_XSH);
    _Float16* Wbu  = (_Float16*)(ws + OFF_WBU);
    _Float16* Wc   = (_Float16*)(ws + OFF_WC);
    _Float16* Wglu = (_Float16*)(ws + OFF_WGLU);
    _Float16* WoutT= (_Float16*)(ws + OFF_WOUT);
    float* bglu = (float*)(ws + OFF_BGLU);
    float* aR  = (float*)(ws + OFF_AR);
    float* aI  = (float*)(ws + OFF_AI);
    float* cbR = (float*)(ws + OFF_CBR);
    float* cbI = (float*)(ws + OFF_CBI);
    float* aTR = (float*)(ws + OFF_ATR);
    float* aTI = (float*)(ws + OFF_ATI);
    float* alp = (float*)(ws + OFF_ALP);
    float* ralp= (float*)(ws + OFF_RALP);
    float* x0  = (float*)(ws + OFF_X0);
    float* carRI=(float*)(ws + OFF_CARRI);

    s5_k0a<<<1, 512, 0, stream>>>(Lre, Lim, lstep, aR, aI, cbR, cbI, aTR, aTI, alp, ralp);
    s5_k0b<<<256, 256, 0, stream>>>(Bre, Bim, Cre, Cim, W1, W2, b1, b2, Wout,
                                    cbR, cbI, alp, ralp, Wbu, Wc, Wglu, WoutT, bglu);
    s5_k0c<<<1, 256, 0, stream>>>(latent, W_expand, b_expand, x0);
    s5_k1_fill<<<8192, 256, 0, stream>>>(x0, x);

    for (int l = 0; l < 4; ++l) {
        s5_k2_ln<<<8192, 256, 0, stream>>>(x, norm_s + l * 256, norm_b + l * 256, hbuf);
        s5_k3_gemm_bu<<<dim3(256, 2), 256, 0, stream>>>(hbuf, Wbu + l * 65536, Bu);
        s5_k4_scan<<<NCH, 128, 0, stream>>>(Bu, aR + l * 128, aI + l * 128, xsh, carRI);
        s5_k6_apply<<<NCH, 128, 0, stream>>>(xsh, carRI, aR + l * 128, aI + l * 128,
                                             aTR + l * 128, aTI + l * 128, xs2);
        s5_k7_gemm_c<<<256, 512, 0, stream>>>(xs2, Wc + l * 65536, hbuf, Dv + l * 256,
                                              norm_s + l * 256, norm_b + l * 256, gbuf);
        s5_k8_gemm_glu<<<dim3(256, 4), 256, 0, stream>>>(gbuf, Wglu + l * 131072,
                                                         bglu + l * 512, x, xh);
    }
    s5_k9_gemm_out<<<256, 256, 0, stream>>>(xh, WoutT, bout, (float*)d_out);
}